// Round 5
// baseline (171.830 us; speedup 1.0000x reference)
//
#include <hip/hip_runtime.h>
#include <hip/hip_bf16.h>
#include <stdint.h>
#include <math.h>

// Attention: out = dropout(softmax(8 * Q K^T)) V, B=4 H=16 S=1024 D=64 fp32.
// R14 = R13 + V-to-registers (latency attack; R13 confirmed wait-bound:
// issue-busy only ~17% of cycles, VALU diet gave counters-not-time):
//  - VtS LDS buffer ELIMINATED. Per wave, the 8 V fragments (16B each) are
//    loaded directly from pre-swizzled Vtg global into registers, issued
//    right after the drain barrier. Vtg is READ-ONLY during attn -> these
//    loads have zero cross-wave ordering constraints (unlike R10's K-LDS
//    pipelining, which raced the __syncthreads vmcnt(0) drain and failed).
//    QK^T + softmax (~1-2K cy) hide the V L2/HBM latency; compiler inserts
//    the vmcnt wait just before PV's first MFMA use.
//  - DMA drain shrinks 6 -> 4 global_load_lds per wave (Kh,Kl only).
//  - PV reads P from LDS (same-wave RAW, unchanged) and V from regs ->
//    PV ds_read waits + V bank conflicts gone. LDS 37.4 -> ~29 KB.
//  - Numerics diet from R13 (bisect-PROVEN safe, absmax 0.03125):
//    native RNE cvts (f2bf_fast), log2-domain softmax (exp2), defer-rescale.
//  - Staging structure for K: R9/R13-proven two-barrier single buffer.
//  - S^T = K Q^T: C-layout col = q -> per-lane softmax state, 2 shuffles/row.
//  - Dropout: deferred correction (candidate list + dense threefry drain).
//    Threefry: counter-mode, bits = y0^y1 (VERIFIED R2); threshold exp(-11).

constexpr int Bn = 4, Hn = 16, Sn = 1024, Dn = 64;
constexpr int NT = 256;
constexpr int TK = 64;
constexpr int TQM = 64;   // main-kernel q tile (wave w owns q rows w*16..w*16+15)
constexpr int CAP = 128;  // per-wave candidate list capacity (overflow path exact)

typedef short s16x8 __attribute__((ext_vector_type(8)));
typedef short s16x4 __attribute__((ext_vector_type(4)));
typedef float f32x4 __attribute__((ext_vector_type(4)));

__device__ __forceinline__ uint16_t f2bf(float x) {  // RNE float->bf16 (manual)
  uint32_t u = __float_as_uint(x);
  return (uint16_t)((u + 0x7fffu + ((u >> 16) & 1u)) >> 16);
}
__device__ __forceinline__ uint16_t f2bf_fast(float x) {  // RNE via v_cvt (fusable)
  return __builtin_bit_cast(uint16_t, __float2bfloat16(x));
}
__device__ __forceinline__ float bf2f(uint16_t h) {
  return __uint_as_float(((uint32_t)h) << 16);
}
__device__ __forceinline__ float fexp2(float x) {  // v_exp_f32 (2^x)
  return __builtin_amdgcn_exp2f(x);
}

__device__ __forceinline__ void tf_round(uint32_t& x0, uint32_t& x1, const int r) {
  x0 += x1;
  x1 = (x1 << r) | (x1 >> (32 - r));
  x1 ^= x0;
}

// threefry2x32, key(42)=(0,42), counter (0, j), bits = y0^y1  [VERIFIED R2]
__device__ __noinline__ int keep_bit(uint32_t j) {
  uint32_t x0 = 0u, x1 = j;
  const uint32_t k0 = 0u, k1v = 42u;
  const uint32_t k2v = k0 ^ k1v ^ 0x1BD11BDAu;
  x0 += k0; x1 += k1v;
  tf_round(x0, x1, 13); tf_round(x0, x1, 15); tf_round(x0, x1, 26); tf_round(x0, x1, 6);
  x0 += k1v; x1 += k2v + 1u;
  tf_round(x0, x1, 17); tf_round(x0, x1, 29); tf_round(x0, x1, 16); tf_round(x0, x1, 24);
  x0 += k2v; x1 += k0 + 2u;
  tf_round(x0, x1, 13); tf_round(x0, x1, 15); tf_round(x0, x1, 26); tf_round(x0, x1, 6);
  x0 += k0; x1 += k1v + 3u;
  tf_round(x0, x1, 17); tf_round(x0, x1, 29); tf_round(x0, x1, 16); tf_round(x0, x1, 24);
  x0 += k1v; x1 += k2v + 4u;
  tf_round(x0, x1, 13); tf_round(x0, x1, 15); tf_round(x0, x1, 26); tf_round(x0, x1, 6);
  x0 += k2v; x1 += k0 + 5u;
  uint32_t bits = x0 ^ x1;
  float u = __uint_as_float((bits >> 9) | 0x3f800000u) - 1.0f;
  return u < 0.9f;
}

// ---------------- pre-pass: K split + V transpose, swizzled bf16 tiles ----------------
__global__ __launch_bounds__(NT) void prep_kv(const float* __restrict__ K,
                                              const float* __restrict__ V,
                                              uint16_t* __restrict__ Khg,
                                              uint16_t* __restrict__ Klg,
                                              uint16_t* __restrict__ Vtg) {
  __shared__ float Vl[TK][Dn + 1];
  const int t = threadIdx.x;
  const int kt = blockIdx.x;   // 0..15
  const int bh = blockIdx.y;   // 0..63
  const int r = t >> 2, qd = t & 3;
  const size_t tile = ((size_t)bh * 16 + kt) * 4096;
  const float* ksrc = K + ((size_t)bh * Sn + (size_t)(kt * TK + r)) * Dn + qd * 16;
  const float* vsrc = V + ((size_t)bh * Sn + (size_t)(kt * TK + r)) * Dn + qd * 16;

#pragma unroll
  for (int half = 0; half < 2; ++half) {
    float4 a = *(const float4*)(ksrc + half * 8);
    float4 b = *(const float4*)(ksrc + half * 8 + 4);
    float xs[8] = {a.x, a.y, a.z, a.w, b.x, b.y, b.z, b.w};
    s16x8 hv, lv;
#pragma unroll
    for (int j = 0; j < 8; ++j) {
      uint16_t hb = f2bf(xs[j]);
      hv[j] = (short)hb;
      lv[j] = (short)f2bf(xs[j] - bf2f(hb));
    }
    const int sc = (qd * 2 + half) ^ (r & 7);
    *(s16x8*)&Khg[tile + (size_t)r * 64 + sc * 8] = hv;
    *(s16x8*)&Klg[tile + (size_t)r * 64 + sc * 8] = lv;
    float4 va = *(const float4*)(vsrc + half * 8);
    float4 vb = *(const float4*)(vsrc + half * 8 + 4);
    *(float4*)&Vl[r][qd * 16 + half * 8] = va;
    *(float4*)&Vl[r][qd * 16 + half * 8 + 4] = vb;
  }
  __syncthreads();
#pragma unroll
  for (int half = 0; half < 2; ++half) {
    s16x8 ov;
#pragma unroll
    for (int j = 0; j < 8; ++j) ov[j] = (short)f2bf(Vl[qd * 16 + half * 8 + j][r]);
    const int sc = (qd * 2 + half) ^ (r & 7);
    *(s16x8*)&Vtg[tile + (size_t)r * 64 + sc * 8] = ov;
  }
}

// ---------------- main flash kernel: S^T orientation, TQ=64, 4 blocks/CU ----------------
__global__ __launch_bounds__(NT, 4) void attn_mfma7(
    const float* __restrict__ Q, const uint16_t* __restrict__ Khg,
    const uint16_t* __restrict__ Klg, const uint16_t* __restrict__ Vtg,
    const float* __restrict__ V, const int* __restrict__ scale_ptr,
    float* __restrict__ out) {
  __shared__ uint16_t KhS[TK * Dn];      // 8 KB, unpadded (DMA dest), swizzled rows
  __shared__ uint16_t KlS[TK * Dn];
  __shared__ uint16_t PS[4 * 16 * 64];   // per-wave P[q][key], XOR-chunk swizzled
  __shared__ uint32_t Lm[4][CAP];        // per-wave candidate list: (rw<<10)|key
  __shared__ float Lsv[4][CAP];          // candidate raw logit s (log2 domain)
  __shared__ float mfin[4][16];          // per-wave final row max (log2 domain)

  const int t = threadIdx.x;
  const int w = t >> 6;
  const int lane = t & 63;
  const int l16 = lane & 15;
  const int quad = lane >> 4;
  const int xl = l16 & 7;                // XOR swizzle key

  const int b = blockIdx.z, h = blockIdx.y;
  const int qbase = blockIdx.x * TQM;
  const int bh = b * Hn + h;
  // log2(e) folded into the Q pre-scale: all logits live in the log2 domain.
  const float qscale = (float)(*scale_ptr) * 1.44269504089f;
  const float pthr = 1.670170079e-5f;    // exp(-11), in the p domain (unchanged)

  // per-wave DMA segment offsets (elements): wave w covers segs {2w, 2w+1}
  const int e0off = (w * 2) * 512 + lane * 8;
  const int e1off = (w * 2 + 1) * 512 + lane * 8;
  const size_t tbase = (size_t)bh * 16 * 4096;
  const int psw = w * 1024;              // per-wave PS base (elements)

  // ---- Q B-frags (pre-scaled, log2 domain): wave w owns q rows qbase+w*16+l16 ----
  s16x8 qh[2], ql[2];
  {
    const int qrow = qbase + w * 16 + l16;
    const float* src = Q + ((size_t)bh * Sn + (size_t)qrow) * Dn;
#pragma unroll
    for (int ks = 0; ks < 2; ++ks) {
      float4 x0 = *(const float4*)(src + ks * 32 + quad * 8);
      float4 x1 = *(const float4*)(src + ks * 32 + quad * 8 + 4);
      float xv[8] = {x0.x, x0.y, x0.z, x0.w, x1.x, x1.y, x1.z, x1.w};
#pragma unroll
      for (int j = 0; j < 8; ++j) {
        const float xs = xv[j] * qscale;
        uint16_t hb = f2bf_fast(xs);
        qh[ks][j] = (short)hb;
        ql[ks][j] = (short)f2bf_fast(xs - bf2f(hb));
      }
    }
  }

  // per-lane softmax state: ONE q per lane (log2 domain)
  float m_r = -INFINITY, l_r = 0.0f;
  // O^T accumulator: o_acc[c][r] = O[q = l16][dv = c*16+quad*4+r]
  f32x4 o_acc[4];
#pragma unroll
  for (int c = 0; c < 4; ++c) o_acc[c] = (f32x4){0.f, 0.f, 0.f, 0.f};

  const uint32_t hbase = (uint32_t)bh * (uint32_t)Sn;
  int lbase = 0;  // per-wave list fill (wave-uniform)

  for (int kt = 0; kt < Sn / TK; ++kt) {
    const int kbase = kt * TK;
    const size_t tile = tbase + (size_t)kt * 4096;
    __syncthreads();  // all waves done reading prev tile's LDS

    // ---- K DMA staging (single buffer; R5/R8/R9/R13-proven structure) ----
    {
      __builtin_amdgcn_global_load_lds(
          (const __attribute__((address_space(1))) uint32_t*)(Khg + tile + e0off),
          (__attribute__((address_space(3))) uint32_t*)(KhS + e0off), 16, 0, 0);
      __builtin_amdgcn_global_load_lds(
          (const __attribute__((address_space(1))) uint32_t*)(Khg + tile + e1off),
          (__attribute__((address_space(3))) uint32_t*)(KhS + e1off), 16, 0, 0);
      __builtin_amdgcn_global_load_lds(
          (const __attribute__((address_space(1))) uint32_t*)(Klg + tile + e0off),
          (__attribute__((address_space(3))) uint32_t*)(KlS + e0off), 16, 0, 0);
      __builtin_amdgcn_global_load_lds(
          (const __attribute__((address_space(1))) uint32_t*)(Klg + tile + e1off),
          (__attribute__((address_space(3))) uint32_t*)(KlS + e1off), 16, 0, 0);
    }
    __syncthreads();  // vmcnt drained -> K deposits visible

    // ---- V fragments: global -> regs (Vtg read-only; no ordering hazard).
    // Issued here so QK + softmax hide the latency; consumed first at PV. ----
    s16x8 vfrag[8];
#pragma unroll
    for (int ks2 = 0; ks2 < 2; ++ks2)
#pragma unroll
      for (int c = 0; c < 4; ++c)
        vfrag[ks2 * 4 + c] = *(const s16x8*)&Vtg[tile +
            (size_t)((c * 16 + l16) * 64 + (((ks2 * 4 + quad) ^ xl) * 8))];

    // ---- S^T = K Q^T: A = K tile (LDS), B = Q (regs), split-bf16 3-MFMA.
    // C-layout: row = key-in-tile = quad*4+r, col = q = l16; c = key-block. ----
    f32x4 sacc[4];
#pragma unroll
    for (int c = 0; c < 4; ++c) sacc[c] = (f32x4){0.f, 0.f, 0.f, 0.f};
#pragma unroll
    for (int ks = 0; ks < 2; ++ks) {
#pragma unroll
      for (int c = 0; c < 4; ++c) {
        const int boff = (c * 16 + l16) * 64 + (((ks * 4 + quad) ^ xl) * 8);
        const s16x8 khv = *(const s16x8*)&KhS[boff];
        const s16x8 klv = *(const s16x8*)&KlS[boff];
        sacc[c] = __builtin_amdgcn_mfma_f32_16x16x32_bf16(khv, qh[ks], sacc[c], 0, 0, 0);
        sacc[c] = __builtin_amdgcn_mfma_f32_16x16x32_bf16(khv, ql[ks], sacc[c], 0, 0, 0);
        sacc[c] = __builtin_amdgcn_mfma_f32_16x16x32_bf16(klv, qh[ks], sacc[c], 0, 0, 0);
      }
    }

    // ---- online softmax (per-lane row state), fused push + P store ----
    {
      float mx = sacc[0][0];
#pragma unroll
      for (int c = 0; c < 4; ++c)
#pragma unroll
        for (int r = 0; r < 4; ++r) mx = fmaxf(mx, sacc[c][r]);
      mx = fmaxf(mx, __shfl_xor(mx, 16));
      mx = fmaxf(mx, __shfl_xor(mx, 32));  // row max over all 64 keys of tile

      // defer-rescale: if no lane's max grew, alpha==1 exactly -> skip the pass
      if (__ballot(mx > m_r) != 0ull) {
        const float mn = fmaxf(m_r, mx);
        const float al = fexp2(m_r - mn);  // 0 on first tile
        m_r = mn;
#pragma unroll
        for (int c = 0; c < 4; ++c)
#pragma unroll
          for (int r = 0; r < 4; ++r) o_acc[c][r] *= al;
        l_r *= al;
      }

      // -15.88 < -11*log2(e) = -15.8696: gate true whenever any pc can exceed pthr
      const bool anyhot = __ballot(mx - m_r > -15.88f) != 0ull;
      float rs = 0.0f;
#pragma unroll
      for (int c = 0; c < 4; ++c) {
        float pc[4];  // only 4 floats live at the pressure peak (reg diet)
#pragma unroll
        for (int r = 0; r < 4; ++r) {
          pc[r] = fexp2(sacc[c][r] - m_r);
          rs += pc[r];  // UNMASKED row sum (softmax normalizes before dropout)
        }
        if (anyhot) {
#pragma unroll
          for (int r = 0; r < 4; ++r) {
            const uint64_t mc = __ballot(pc[r] > pthr);
            if (mc != 0ull) {
              if (lbase + 64 <= CAP) {
                const int slot = lbase + (int)__popcll(mc & ((1ull << lane) - 1ull));
                if (pc[r] > pthr) {
                  Lm[w][slot] = ((uint32_t)l16 << 10) |
                                (uint32_t)(kbase + c * 16 + quad * 4 + r);
                  Lsv[w][slot] = sacc[c][r];  // raw logit (log2 domain)
                }
                lbase += (int)__popcll(mc);
              } else if (pc[r] > pthr) {  // overflow: inline exact dropout
                const uint32_t j =
                    (hbase + (uint32_t)(qbase + w * 16 + l16)) * (uint32_t)Sn +
                    (uint32_t)(kbase + c * 16 + quad * 4 + r);
                if (!keep_bit(j)) pc[r] = 0.0f;  // rs already added (unmasked)
              }
            }
          }
        }
        // P store: 4 consecutive keys -> b64, XOR-chunk swizzled (native cvt)
        s16x4 pk;
#pragma unroll
        for (int r = 0; r < 4; ++r) pk[r] = (short)f2bf_fast(pc[r]);
        const int pos = (c * 2 + (quad >> 1)) ^ xl;
        *(s16x4*)&PS[psw + l16 * 64 + pos * 8 + (quad & 1) * 4] = pk;
      }

      rs += __shfl_xor(rs, 16);
      rs += __shfl_xor(rs, 32);
      l_r += rs;
    }

    // ---- PV as O^T: A = V frags (regs), B = P (LDS, same-wave RAW) ----
#pragma unroll
    for (int ks2 = 0; ks2 < 2; ++ks2) {
      const s16x8 pb = *(const s16x8*)&PS[psw + l16 * 64 + (((ks2 * 4 + quad) ^ xl) * 8)];
#pragma unroll
      for (int c = 0; c < 4; ++c) {
        o_acc[c] = __builtin_amdgcn_mfma_f32_16x16x32_bf16(vfrag[ks2 * 4 + c], pb,
                                                           o_acc[c], 0, 0, 0);
      }
    }
  }

  // ---- drain: dense threefry over candidate list, subtract dropped p*V ----
  if (quad == 0) mfin[w][l16] = m_r;
  for (int e0 = 0; e0 < lbase; e0 += 64) {
    const int e = e0 + lane;
    const bool valid = e < lbase;
    const uint32_t meta = valid ? Lm[w][e] : 0u;
    const float sv = valid ? Lsv[w][e] : 0.0f;
    const uint32_t rwv = meta >> 10, keyv = meta & 1023u;
    const uint32_t grow = (uint32_t)(qbase + w * 16) + rwv;
    const uint32_t j = (hbase + grow) * (uint32_t)Sn + keyv;
    const int kb = keep_bit(j);  // dense: all 64 lanes productive
    uint64_t dm = __ballot(valid && !kb);
    while (dm != 0ull) {
      const int src = (int)__builtin_ctzll(dm);
      dm &= dm - 1ull;
      const uint32_t meta_s = (uint32_t)__builtin_amdgcn_readlane((int)meta, src);
      const float sv_s =
          __uint_as_float((uint32_t)__builtin_amdgcn_readlane((int)__float_as_uint(sv), src));
      const int rw = (int)(meta_s >> 10);
      const int key = (int)(meta_s & 1023u);
      const float p = fexp2(sv_s - mfin[w][rw]);   // log2 domain
      const float pb2 = bf2f(f2bf_fast(p));        // matches stored bf16(P) bits
      if (rw == l16) {  // the 4 quads owning column q participate
        const float* vp = V + ((size_t)bh * Sn + (size_t)key) * Dn;
#pragma unroll
        for (int c = 0; c < 4; ++c) {
          float4 vv = *(const float4*)(vp + c * 16 + quad * 4);
          o_acc[c][0] = fmaf(-pb2, bf2f(f2bf(vv.x)), o_acc[c][0]);
          o_acc[c][1] = fmaf(-pb2, bf2f(f2bf(vv.y)), o_acc[c][1]);
          o_acc[c][2] = fmaf(-pb2, bf2f(f2bf(vv.z)), o_acc[c][2]);
          o_acc[c][3] = fmaf(-pb2, bf2f(f2bf(vv.w)), o_acc[c][3]);
        }
      }
    }
  }

  // ---- epilogue: out[q][dv] = O^T / (l * 0.9); per-lane scalar scale ----
  {
    const float inv = 1.0f / (l_r * 0.9f);
    const size_t obase = ((size_t)bh * Sn + (size_t)(qbase + w * 16 + l16)) * Dn;
#pragma unroll
    for (int c = 0; c < 4; ++c) {
      float4 ov;
      ov.x = o_acc[c][0] * inv;
      ov.y = o_acc[c][1] * inv;
      ov.z = o_acc[c][2] * inv;
      ov.w = o_acc[c][3] * inv;
      *(float4*)(out + obase + c * 16 + quad * 4) = ov;
    }
  }
}

// ---------------- fallback (R3 kernel, verbatim): used only if ws too small ----------------
constexpr int KST = 72;
__global__ __launch_bounds__(NT) void attn_fallback(
    const float* __restrict__ Q, const float* __restrict__ K,
    const float* __restrict__ V, const int* __restrict__ scale_ptr,
    float* __restrict__ out) {
  __shared__ uint16_t KhS[64 * KST];
  __shared__ uint16_t KlS[64 * KST];
  __shared__ uint16_t VtS[Dn * KST];
  __shared__ uint16_t PSf[4 * 16 * KST];

  const int t = threadIdx.x;
  const int w = t >> 6;
  const int lane = t & 63;
  const int l16 = lane & 15;
  const int quad = lane >> 4;
  const int b = blockIdx.z, h = blockIdx.y;
  const int qbase = blockIdx.x * 64;
  const size_t bh = (size_t)b * Hn + h;
  const float scale = (float)(*scale_ptr);
  const float* Kp = K + bh * Sn * Dn;
  const float* Vp = V + bh * Sn * Dn;

  const int qrow = qbase + w * 16 + l16;
  const float* Qp = Q + (bh * Sn + (size_t)qrow) * Dn;
  s16x8 qh[2], ql[2];
#pragma unroll
  for (int ks = 0; ks < 2; ++ks) {
    const float* src = Qp + ks * 32 + quad * 8;
    float4 x0 = *(const float4*)(src);
    float4 x1 = *(const float4*)(src + 4);
    float xv[8] = {x0.x, x0.y, x0.z, x0.w, x1.x, x1.y, x1.z, x1.w};
#pragma unroll
    for (int j = 0; j < 8; ++j) {
      uint16_t hb = f2bf(xv[j]);
      qh[ks][j] = (short)hb;
      ql[ks][j] = (short)f2bf(xv[j] - bf2f(hb));
    }
  }
  const int kr = t >> 2;
  const int qd = t & 3;
  float m_r[4], l_r[4];
#pragma unroll
  for (int r = 0; r < 4; ++r) { m_r[r] = -INFINITY; l_r[r] = 0.0f; }
  f32x4 o_acc[4];
#pragma unroll
  for (int c = 0; c < 4; ++c) o_acc[c] = (f32x4){0.f, 0.f, 0.f, 0.f};
  const uint32_t rowlin = ((uint32_t)(b * Hn + h)) * (uint32_t)Sn +
                          (uint32_t)(qbase + w * 16 + quad * 4);
  for (int kt = 0; kt < Sn / 64; ++kt) {
    const int kbase = kt * 64;
    __syncthreads();
    {
      const float* ksrc = Kp + (size_t)(kbase + kr) * Dn + qd * 16;
#pragma unroll
      for (int half = 0; half < 2; ++half) {
        float4 a = *(const float4*)(ksrc + half * 8);
        float4 b2 = *(const float4*)(ksrc + half * 8 + 4);
        float xs[8] = {a.x, a.y, a.z, a.w, b2.x, b2.y, b2.z, b2.w};
        s16x8 hv, lv;
#pragma unroll
        for (int j = 0; j < 8; ++j) {
          uint16_t hb = f2bf(xs[j]);
          hv[j] = (short)hb;
          lv[j] = (short)f2bf(xs[j] - bf2f(hb));
        }
        *(s16x8*)&KhS[kr * KST + qd * 16 + half * 8] = hv;
        *(s16x8*)&KlS[kr * KST + qd * 16 + half * 8] = lv;
      }
      const float* vsrc = Vp + (size_t)(kbase + kr) * Dn + qd * 16;
#pragma unroll
      for (int half = 0; half < 2; ++half) {
        float4 a = *(const float4*)(vsrc + half * 8);
        float4 b2 = *(const float4*)(vsrc + half * 8 + 4);
        float xs[8] = {a.x, a.y, a.z, a.w, b2.x, b2.y, b2.z, b2.w};
#pragma unroll
        for (int j = 0; j < 8; ++j)
          VtS[(qd * 16 + half * 8 + j) * KST + kr] = f2bf(xs[j]);
      }
    }
    __syncthreads();
    f32x4 sacc[4];
#pragma unroll
    for (int c = 0; c < 4; ++c) sacc[c] = (f32x4){0.f, 0.f, 0.f, 0.f};
#pragma unroll
    for (int ks = 0; ks < 2; ++ks) {
#pragma unroll
      for (int c = 0; c < 4; ++c) {
        const s16x8 bh_ = *(const s16x8*)&KhS[(c * 16 + l16) * KST + ks * 32 + quad * 8];
        const s16x8 bl_ = *(const s16x8*)&KlS[(c * 16 + l16) * KST + ks * 32 + quad * 8];
        sacc[c] = __builtin_amdgcn_mfma_f32_16x16x32_bf16(qh[ks], bh_, sacc[c], 0, 0, 0);
        sacc[c] = __builtin_amdgcn_mfma_f32_16x16x32_bf16(ql[ks], bh_, sacc[c], 0, 0, 0);
        sacc[c] = __builtin_amdgcn_mfma_f32_16x16x32_bf16(qh[ks], bl_, sacc[c], 0, 0, 0);
      }
    }
    float mx[4];
#pragma unroll
    for (int r = 0; r < 4; ++r) {
      mx[r] = sacc[0][r] * scale;
#pragma unroll
      for (int c = 1; c < 4; ++c) mx[r] = fmaxf(mx[r], sacc[c][r] * scale);
#pragma unroll
      for (int d = 1; d < 16; d <<= 1) mx[r] = fmaxf(mx[r], __shfl_xor(mx[r], d));
    }
    float al[4];
#pragma unroll
    for (int r = 0; r < 4; ++r) {
      const float mn = fmaxf(m_r[r], mx[r]);
      al[r] = __expf(m_r[r] - mn);
      m_r[r] = mn;
    }
#pragma unroll
    for (int c = 0; c < 4; ++c)
#pragma unroll
      for (int r = 0; r < 4; ++r) o_acc[c][r] *= al[r];
    float rs[4] = {0.f, 0.f, 0.f, 0.f};
#pragma unroll
    for (int c = 0; c < 4; ++c) {
#pragma unroll
      for (int r = 0; r < 4; ++r) {
        const float d = sacc[c][r] * scale - m_r[r];
        float pv = __expf(d);
        rs[r] += pv;
        if (d > -25.0f) {
          const uint32_t j = (rowlin + (uint32_t)r) * (uint32_t)Sn +
                             (uint32_t)(kbase + c * 16 + l16);
          if (!keep_bit(j)) pv = 0.0f;
        }
        PSf[(w * 16 + quad * 4 + r) * KST + c * 16 + l16] = f2bf(pv);
      }
    }
#pragma unroll
    for (int r = 0; r < 4; ++r) {
#pragma unroll
      for (int d = 1; d < 16; d <<= 1) rs[r] += __shfl_xor(rs[r], d);
      l_r[r] = l_r[r] * al[r] + rs[r];
    }
#pragma unroll
    for (int ks2 = 0; ks2 < 2; ++ks2) {
      const s16x8 pa = *(const s16x8*)&PSf[(w * 16 + l16) * KST + ks2 * 32 + quad * 8];
#pragma unroll
      for (int c = 0; c < 4; ++c) {
        const s16x8 vb = *(const s16x8*)&VtS[(c * 16 + l16) * KST + ks2 * 32 + quad * 8];
        o_acc[c] = __builtin_amdgcn_mfma_f32_16x16x32_bf16(pa, vb, o_acc[c], 0, 0, 0);
      }
    }
  }
  float inv[4];
#pragma unroll
  for (int r = 0; r < 4; ++r) inv[r] = 1.0f / (l_r[r] * 0.9f);
#pragma unroll
  for (int c = 0; c < 4; ++c)
#pragma unroll
    for (int r = 0; r < 4; ++r)
      out[(bh * Sn + (size_t)(qbase + w * 16 + quad * 4 + r)) * Dn + c * 16 + l16] =
          o_acc[c][r] * inv[r];
}

extern "C" void kernel_launch(void* const* d_in, const int* in_sizes, int n_in,
                              void* d_out, int out_size, void* d_ws, size_t ws_size,
                              hipStream_t stream) {
  const float* Q = (const float*)d_in[0];
  const float* K = (const float*)d_in[1];
  const float* V = (const float*)d_in[2];
  const int* sf = (const int*)d_in[3];
  float* out = (float*)d_out;

  constexpr size_t ARR = (size_t)Bn * Hn * Sn * Dn;  // 4,194,304 elems (8 MB bf16)
  const size_t need = 3 * ARR * sizeof(uint16_t);    // 24 MB

  if (ws_size >= need) {
    uint16_t* Khg = (uint16_t*)d_ws;
    uint16_t* Klg = Khg + ARR;
    uint16_t* Vtg = Klg + ARR;
    prep_kv<<<dim3(16, 64), NT, 0, stream>>>(K, V, Khg, Klg, Vtg);
    attn_mfma7<<<dim3(Sn / TQM, Hn, Bn), NT, 0, stream>>>(Q, Khg, Klg, Vtg, V, sf, out);
  } else {
    attn_fallback<<<dim3(Sn / 64, Hn, Bn), NT, 0, stream>>>(Q, K, V, sf, out);
  }
}

// Round 7
// 162.345 us; speedup vs baseline: 1.0584x; 1.0584x over previous
//
#include <hip/hip_runtime.h>
#include <hip/hip_bf16.h>
#include <stdint.h>
#include <math.h>

// Attention: out = dropout(softmax(8 * Q K^T)) V, B=4 H=16 S=1024 D=64 fp32.
// R16 = R15 resubmitted verbatim (R15 hit "MI355X container failed twice" —
// broker-level, pre-compile; precedent: R11/R12 same error, identical source
// then PASSED as R13). Audit: no deadlock surface (unconditional barriers,
// fixed-trip loops, wave-uniform branches, LDS 72.5KB*2 <= 160KB).
// R15 = R13 + single-barrier double-buffered ping-pong staging (T3 2-phase,
// HW-verified recipe), NT 256->512 to pay the LDS without losing waves/CU.
//  - R14 (V-to-regs) REVERTED: it quadrupled per-block V traffic (each wave
//    loaded the full 8KB tile; LDS staging deduplicated across waves) and
//    regressed 86.4 -> 91.3 us. V back in LDS.
//  - Ping-pong: issue K,V(kt+1)->buf[p^1] right after the barrier, compute
//    tile kt from buf[p], ONE barrier per tile. The prefetch never writes a
//    buffer read in the current interval (R10's failure wrote the SAME
//    buffer PV was about to read -> raced; this never does). Visibility =
//    compiler's own vmcnt(0)+lgkmcnt(0) drain before each s_barrier, the
//    exact mechanism R9/R13 rely on. DMA latency hides under QK+softmax+PV.
//    Barriers/tile 2 -> 1 (32 -> 16 per kernel).
//  - NT=512 (8 waves), TQM=128, grid 512 = 2 blocks/CU x 8 waves = 16
//    waves/CU (same as R13's 4x4). LDS 72.5KB/block (145KB/CU <= 160KB).
//    Halved q-block count also halves K/V re-read traffic.
//  - Numerics diet from R13 (bisect-PROVEN safe, absmax 0.03125):
//    native RNE cvts (f2bf_fast), log2-domain softmax (exp2), defer-rescale.
//  - S^T = K Q^T: C-layout col = q -> per-lane softmax state, 2 shuffles/row.
//  - Dropout: deferred correction (candidate list + dense threefry drain).
//    Threefry: counter-mode, bits = y0^y1 (VERIFIED R2); threshold exp(-11).

constexpr int Bn = 4, Hn = 16, Sn = 1024, Dn = 64;
constexpr int NT = 512;   // main kernel: 8 waves/block
constexpr int NTF = 256;  // prep + fallback block size
constexpr int TK = 64;
constexpr int TQM = 128;  // q rows per block (wave w owns rows w*16..w*16+15)
constexpr int CAP = 128;  // per-wave candidate list capacity (overflow path exact)
constexpr int NTILE = Sn / TK;  // 16

typedef short s16x8 __attribute__((ext_vector_type(8)));
typedef short s16x4 __attribute__((ext_vector_type(4)));
typedef float f32x4 __attribute__((ext_vector_type(4)));

__device__ __forceinline__ uint16_t f2bf(float x) {  // RNE float->bf16 (manual)
  uint32_t u = __float_as_uint(x);
  return (uint16_t)((u + 0x7fffu + ((u >> 16) & 1u)) >> 16);
}
__device__ __forceinline__ uint16_t f2bf_fast(float x) {  // RNE via v_cvt (fusable)
  return __builtin_bit_cast(uint16_t, __float2bfloat16(x));
}
__device__ __forceinline__ float bf2f(uint16_t h) {
  return __uint_as_float(((uint32_t)h) << 16);
}
__device__ __forceinline__ float fexp2(float x) {  // v_exp_f32 (2^x)
  return __builtin_amdgcn_exp2f(x);
}

__device__ __forceinline__ void tf_round(uint32_t& x0, uint32_t& x1, const int r) {
  x0 += x1;
  x1 = (x1 << r) | (x1 >> (32 - r));
  x1 ^= x0;
}

// threefry2x32, key(42)=(0,42), counter (0, j), bits = y0^y1  [VERIFIED R2]
__device__ __noinline__ int keep_bit(uint32_t j) {
  uint32_t x0 = 0u, x1 = j;
  const uint32_t k0 = 0u, k1v = 42u;
  const uint32_t k2v = k0 ^ k1v ^ 0x1BD11BDAu;
  x0 += k0; x1 += k1v;
  tf_round(x0, x1, 13); tf_round(x0, x1, 15); tf_round(x0, x1, 26); tf_round(x0, x1, 6);
  x0 += k1v; x1 += k2v + 1u;
  tf_round(x0, x1, 17); tf_round(x0, x1, 29); tf_round(x0, x1, 16); tf_round(x0, x1, 24);
  x0 += k2v; x1 += k0 + 2u;
  tf_round(x0, x1, 13); tf_round(x0, x1, 15); tf_round(x0, x1, 26); tf_round(x0, x1, 6);
  x0 += k0; x1 += k1v + 3u;
  tf_round(x0, x1, 17); tf_round(x0, x1, 29); tf_round(x0, x1, 16); tf_round(x0, x1, 24);
  x0 += k1v; x1 += k2v + 4u;
  tf_round(x0, x1, 13); tf_round(x0, x1, 15); tf_round(x0, x1, 26); tf_round(x0, x1, 6);
  x0 += k2v; x1 += k0 + 5u;
  uint32_t bits = x0 ^ x1;
  float u = __uint_as_float((bits >> 9) | 0x3f800000u) - 1.0f;
  return u < 0.9f;
}

// ---------------- pre-pass: K split + V transpose, swizzled bf16 tiles ----------------
__global__ __launch_bounds__(NTF) void prep_kv(const float* __restrict__ K,
                                               const float* __restrict__ V,
                                               uint16_t* __restrict__ Khg,
                                               uint16_t* __restrict__ Klg,
                                               uint16_t* __restrict__ Vtg) {
  __shared__ float Vl[TK][Dn + 1];
  const int t = threadIdx.x;
  const int kt = blockIdx.x;   // 0..15
  const int bh = blockIdx.y;   // 0..63
  const int r = t >> 2, qd = t & 3;
  const size_t tile = ((size_t)bh * 16 + kt) * 4096;
  const float* ksrc = K + ((size_t)bh * Sn + (size_t)(kt * TK + r)) * Dn + qd * 16;
  const float* vsrc = V + ((size_t)bh * Sn + (size_t)(kt * TK + r)) * Dn + qd * 16;

#pragma unroll
  for (int half = 0; half < 2; ++half) {
    float4 a = *(const float4*)(ksrc + half * 8);
    float4 b = *(const float4*)(ksrc + half * 8 + 4);
    float xs[8] = {a.x, a.y, a.z, a.w, b.x, b.y, b.z, b.w};
    s16x8 hv, lv;
#pragma unroll
    for (int j = 0; j < 8; ++j) {
      uint16_t hb = f2bf(xs[j]);
      hv[j] = (short)hb;
      lv[j] = (short)f2bf(xs[j] - bf2f(hb));
    }
    const int sc = (qd * 2 + half) ^ (r & 7);
    *(s16x8*)&Khg[tile + (size_t)r * 64 + sc * 8] = hv;
    *(s16x8*)&Klg[tile + (size_t)r * 64 + sc * 8] = lv;
    float4 va = *(const float4*)(vsrc + half * 8);
    float4 vb = *(const float4*)(vsrc + half * 8 + 4);
    *(float4*)&Vl[r][qd * 16 + half * 8] = va;
    *(float4*)&Vl[r][qd * 16 + half * 8 + 4] = vb;
  }
  __syncthreads();
#pragma unroll
  for (int half = 0; half < 2; ++half) {
    s16x8 ov;
#pragma unroll
    for (int j = 0; j < 8; ++j) ov[j] = (short)f2bf(Vl[qd * 16 + half * 8 + j][r]);
    const int sc = (qd * 2 + half) ^ (r & 7);
    *(s16x8*)&Vtg[tile + (size_t)r * 64 + sc * 8] = ov;
  }
}

// -------- main flash kernel: S^T orientation, TQ=128, 8 waves, dbuf ping-pong --------
__global__ __launch_bounds__(NT, 4) void attn_mfma7(
    const float* __restrict__ Q, const uint16_t* __restrict__ Khg,
    const uint16_t* __restrict__ Klg, const uint16_t* __restrict__ Vtg,
    const float* __restrict__ V, const int* __restrict__ scale_ptr,
    float* __restrict__ out) {
  __shared__ uint16_t KhS[2][TK * Dn];   // 2 x 8 KB ping-pong (DMA dest, swizzled)
  __shared__ uint16_t KlS[2][TK * Dn];
  __shared__ uint16_t VtS[2][TK * Dn];
  __shared__ uint16_t PS[8 * 16 * 64];   // per-wave P[q][key], XOR-chunk swizzled
  __shared__ uint32_t Lm[8][CAP];        // per-wave candidate list: (rw<<10)|key
  __shared__ float Lsv[8][CAP];          // candidate raw logit s (log2 domain)
  __shared__ float mfin[8][16];          // per-wave final row max (log2 domain)

  const int t = threadIdx.x;
  const int w = t >> 6;                  // 0..7
  const int lane = t & 63;
  const int l16 = lane & 15;
  const int quad = lane >> 4;
  const int xl = l16 & 7;                // XOR swizzle key

  const int b = blockIdx.z, h = blockIdx.y;
  const int qbase = blockIdx.x * TQM;
  const int bh = b * Hn + h;
  // log2(e) folded into the Q pre-scale: all logits live in the log2 domain.
  const float qscale = (float)(*scale_ptr) * 1.44269504089f;
  const float pthr = 1.670170079e-5f;    // exp(-11), in the p domain (unchanged)

  // per-wave DMA segment: wave w covers elements [w*512, w*512+512) of each tile
  const int eoff = w * 512 + lane * 8;
  const size_t tbase = (size_t)bh * 16 * 4096;
  const int psw = w * 1024;              // per-wave PS base (elements)

  auto issue3 = [&](int ti, int pb) {    // stage Kh,Kl,Vt of tile ti into buf pb
    const size_t tile = tbase + (size_t)ti * 4096;
    __builtin_amdgcn_global_load_lds(
        (const __attribute__((address_space(1))) uint32_t*)(Khg + tile + eoff),
        (__attribute__((address_space(3))) uint32_t*)(&KhS[pb][eoff]), 16, 0, 0);
    __builtin_amdgcn_global_load_lds(
        (const __attribute__((address_space(1))) uint32_t*)(Klg + tile + eoff),
        (__attribute__((address_space(3))) uint32_t*)(&KlS[pb][eoff]), 16, 0, 0);
    __builtin_amdgcn_global_load_lds(
        (const __attribute__((address_space(1))) uint32_t*)(Vtg + tile + eoff),
        (__attribute__((address_space(3))) uint32_t*)(&VtS[pb][eoff]), 16, 0, 0);
  };

  // prologue: tile 0 -> buf0 in flight; Q load/split overlaps it
  issue3(0, 0);

  // ---- Q B-frags (pre-scaled, log2 domain): wave w owns q rows qbase+w*16+l16 ----
  s16x8 qh[2], ql[2];
  {
    const int qrow = qbase + w * 16 + l16;
    const float* src = Q + ((size_t)bh * Sn + (size_t)qrow) * Dn;
#pragma unroll
    for (int ks = 0; ks < 2; ++ks) {
      float4 x0 = *(const float4*)(src + ks * 32 + quad * 8);
      float4 x1 = *(const float4*)(src + ks * 32 + quad * 8 + 4);
      float xv[8] = {x0.x, x0.y, x0.z, x0.w, x1.x, x1.y, x1.z, x1.w};
#pragma unroll
      for (int j = 0; j < 8; ++j) {
        const float xs = xv[j] * qscale;
        uint16_t hb = f2bf_fast(xs);
        qh[ks][j] = (short)hb;
        ql[ks][j] = (short)f2bf_fast(xs - bf2f(hb));
      }
    }
  }

  // per-lane softmax state: ONE q per lane (log2 domain)
  float m_r = -INFINITY, l_r = 0.0f;
  // O^T accumulator: o_acc[c][r] = O[q = l16][dv = c*16+quad*4+r]
  f32x4 o_acc[4];
#pragma unroll
  for (int c = 0; c < 4; ++c) o_acc[c] = (f32x4){0.f, 0.f, 0.f, 0.f};

  const uint32_t hbase = (uint32_t)bh * (uint32_t)Sn;
  int lbase = 0;  // per-wave list fill (wave-uniform)

  // one tile's QK -> softmax -> PV, reading buffers [pb]
  auto tile_step = [&](int kbase, int pb) {
    // ---- S^T = K Q^T: A = K tile (LDS), B = Q (regs), split-bf16 3-MFMA ----
    f32x4 sacc[4];
#pragma unroll
    for (int c = 0; c < 4; ++c) sacc[c] = (f32x4){0.f, 0.f, 0.f, 0.f};
#pragma unroll
    for (int ks = 0; ks < 2; ++ks) {
#pragma unroll
      for (int c = 0; c < 4; ++c) {
        const int boff = (c * 16 + l16) * 64 + (((ks * 4 + quad) ^ xl) * 8);
        const s16x8 khv = *(const s16x8*)&KhS[pb][boff];
        const s16x8 klv = *(const s16x8*)&KlS[pb][boff];
        sacc[c] = __builtin_amdgcn_mfma_f32_16x16x32_bf16(khv, qh[ks], sacc[c], 0, 0, 0);
        sacc[c] = __builtin_amdgcn_mfma_f32_16x16x32_bf16(khv, ql[ks], sacc[c], 0, 0, 0);
        sacc[c] = __builtin_amdgcn_mfma_f32_16x16x32_bf16(klv, qh[ks], sacc[c], 0, 0, 0);
      }
    }

    // ---- online softmax (per-lane row state), fused push + P store ----
    {
      float mx = sacc[0][0];
#pragma unroll
      for (int c = 0; c < 4; ++c)
#pragma unroll
        for (int r = 0; r < 4; ++r) mx = fmaxf(mx, sacc[c][r]);
      mx = fmaxf(mx, __shfl_xor(mx, 16));
      mx = fmaxf(mx, __shfl_xor(mx, 32));  // row max over all 64 keys of tile

      // defer-rescale: if no lane's max grew, alpha==1 exactly -> skip the pass
      if (__ballot(mx > m_r) != 0ull) {
        const float mn = fmaxf(m_r, mx);
        const float al = fexp2(m_r - mn);  // 0 on first tile
        m_r = mn;
#pragma unroll
        for (int c = 0; c < 4; ++c)
#pragma unroll
          for (int r = 0; r < 4; ++r) o_acc[c][r] *= al;
        l_r *= al;
      }

      // -15.88 < -11*log2(e): gate true whenever any pc can exceed pthr
      const bool anyhot = __ballot(mx - m_r > -15.88f) != 0ull;
      float rs = 0.0f;
#pragma unroll
      for (int c = 0; c < 4; ++c) {
        float pc[4];  // only 4 floats live at the pressure peak (reg diet)
#pragma unroll
        for (int r = 0; r < 4; ++r) {
          pc[r] = fexp2(sacc[c][r] - m_r);
          rs += pc[r];  // UNMASKED row sum (softmax normalizes before dropout)
        }
        if (anyhot) {
#pragma unroll
          for (int r = 0; r < 4; ++r) {
            const uint64_t mc = __ballot(pc[r] > pthr);
            if (mc != 0ull) {
              if (lbase + 64 <= CAP) {
                const int slot = lbase + (int)__popcll(mc & ((1ull << lane) - 1ull));
                if (pc[r] > pthr) {
                  Lm[w][slot] = ((uint32_t)l16 << 10) |
                                (uint32_t)(kbase + c * 16 + quad * 4 + r);
                  Lsv[w][slot] = sacc[c][r];  // raw logit (log2 domain)
                }
                lbase += (int)__popcll(mc);
              } else if (pc[r] > pthr) {  // overflow: inline exact dropout
                const uint32_t j =
                    (hbase + (uint32_t)(qbase + w * 16 + l16)) * (uint32_t)Sn +
                    (uint32_t)(kbase + c * 16 + quad * 4 + r);
                if (!keep_bit(j)) pc[r] = 0.0f;  // rs already added (unmasked)
              }
            }
          }
        }
        // P store: 4 consecutive keys -> b64, XOR-chunk swizzled (native cvt)
        s16x4 pk;
#pragma unroll
        for (int r = 0; r < 4; ++r) pk[r] = (short)f2bf_fast(pc[r]);
        const int pos = (c * 2 + (quad >> 1)) ^ xl;
        *(s16x4*)&PS[psw + l16 * 64 + pos * 8 + (quad & 1) * 4] = pk;
      }

      rs += __shfl_xor(rs, 16);
      rs += __shfl_xor(rs, 32);
      l_r += rs;
    }

    // ---- PV as O^T: A = Vt (LDS), B = P (LDS, same-wave RAW) ----
#pragma unroll
    for (int ks2 = 0; ks2 < 2; ++ks2) {
      const s16x8 pfr = *(const s16x8*)&PS[psw + l16 * 64 + (((ks2 * 4 + quad) ^ xl) * 8)];
#pragma unroll
      for (int c = 0; c < 4; ++c) {
        const int voff = (c * 16 + l16) * 64 + (((ks2 * 4 + quad) ^ xl) * 8);
        const s16x8 vb = *(const s16x8*)&VtS[pb][voff];
        o_acc[c] = __builtin_amdgcn_mfma_f32_16x16x32_bf16(vb, pfr, o_acc[c], 0, 0, 0);
      }
    }
  };

  // ---- ping-pong main loop: ONE barrier per tile, prefetch into other buffer ----
  for (int kt = 0; kt < NTILE; kt += 2) {
    __syncthreads();               // own vmcnt(0) drained -> buf0(kt) visible to all;
                                   // all waves done reading buf1 (tile kt-1)
    issue3(kt + 1, 1);             // kt+1 <= 15 always (NTILE even)
    tile_step(kt * TK, 0);
    __syncthreads();               // buf1(kt+1) visible; all done reading buf0(kt)
    if (kt + 2 < NTILE) issue3(kt + 2, 0);
    tile_step((kt + 1) * TK, 1);
  }

  // ---- drain: dense threefry over candidate list, subtract dropped p*V ----
  if (quad == 0) mfin[w][l16] = m_r;
  for (int e0 = 0; e0 < lbase; e0 += 64) {
    const int e = e0 + lane;
    const bool valid = e < lbase;
    const uint32_t meta = valid ? Lm[w][e] : 0u;
    const float sv = valid ? Lsv[w][e] : 0.0f;
    const uint32_t rwv = meta >> 10, keyv = meta & 1023u;
    const uint32_t grow = (uint32_t)(qbase + w * 16) + rwv;
    const uint32_t j = (hbase + grow) * (uint32_t)Sn + keyv;
    const int kb = keep_bit(j);  // dense: all 64 lanes productive
    uint64_t dm = __ballot(valid && !kb);
    while (dm != 0ull) {
      const int src = (int)__builtin_ctzll(dm);
      dm &= dm - 1ull;
      const uint32_t meta_s = (uint32_t)__builtin_amdgcn_readlane((int)meta, src);
      const float sv_s =
          __uint_as_float((uint32_t)__builtin_amdgcn_readlane((int)__float_as_uint(sv), src));
      const int rw = (int)(meta_s >> 10);
      const int key = (int)(meta_s & 1023u);
      const float p = fexp2(sv_s - mfin[w][rw]);   // log2 domain
      const float pb2 = bf2f(f2bf_fast(p));        // matches stored bf16(P) bits
      if (rw == l16) {  // the 4 quads owning column q participate
        const float* vp = V + ((size_t)bh * Sn + (size_t)key) * Dn;
#pragma unroll
        for (int c = 0; c < 4; ++c) {
          float4 vv = *(const float4*)(vp + c * 16 + quad * 4);
          o_acc[c][0] = fmaf(-pb2, bf2f(f2bf(vv.x)), o_acc[c][0]);
          o_acc[c][1] = fmaf(-pb2, bf2f(f2bf(vv.y)), o_acc[c][1]);
          o_acc[c][2] = fmaf(-pb2, bf2f(f2bf(vv.z)), o_acc[c][2]);
          o_acc[c][3] = fmaf(-pb2, bf2f(f2bf(vv.w)), o_acc[c][3]);
        }
      }
    }
  }

  // ---- epilogue: out[q][dv] = O^T / (l * 0.9); per-lane scalar scale ----
  {
    const float inv = 1.0f / (l_r * 0.9f);
    const size_t obase = ((size_t)bh * Sn + (size_t)(qbase + w * 16 + l16)) * Dn;
#pragma unroll
    for (int c = 0; c < 4; ++c) {
      float4 ov;
      ov.x = o_acc[c][0] * inv;
      ov.y = o_acc[c][1] * inv;
      ov.z = o_acc[c][2] * inv;
      ov.w = o_acc[c][3] * inv;
      *(float4*)(out + obase + c * 16 + quad * 4) = ov;
    }
  }
}

// ---------------- fallback (R3 kernel, verbatim): used only if ws too small ----------------
constexpr int KST = 72;
__global__ __launch_bounds__(NTF) void attn_fallback(
    const float* __restrict__ Q, const float* __restrict__ K,
    const float* __restrict__ V, const int* __restrict__ scale_ptr,
    float* __restrict__ out) {
  __shared__ uint16_t KhS[64 * KST];
  __shared__ uint16_t KlS[64 * KST];
  __shared__ uint16_t VtS[Dn * KST];
  __shared__ uint16_t PSf[4 * 16 * KST];

  const int t = threadIdx.x;
  const int w = t >> 6;
  const int lane = t & 63;
  const int l16 = lane & 15;
  const int quad = lane >> 4;
  const int b = blockIdx.z, h = blockIdx.y;
  const int qbase = blockIdx.x * 64;
  const size_t bh = (size_t)b * Hn + h;
  const float scale = (float)(*scale_ptr);
  const float* Kp = K + bh * Sn * Dn;
  const float* Vp = V + bh * Sn * Dn;

  const int qrow = qbase + w * 16 + l16;
  const float* Qp = Q + (bh * Sn + (size_t)qrow) * Dn;
  s16x8 qh[2], ql[2];
#pragma unroll
  for (int ks = 0; ks < 2; ++ks) {
    const float* src = Qp + ks * 32 + quad * 8;
    float4 x0 = *(const float4*)(src);
    float4 x1 = *(const float4*)(src + 4);
    float xv[8] = {x0.x, x0.y, x0.z, x0.w, x1.x, x1.y, x1.z, x1.w};
#pragma unroll
    for (int j = 0; j < 8; ++j) {
      uint16_t hb = f2bf(xv[j]);
      qh[ks][j] = (short)hb;
      ql[ks][j] = (short)f2bf(xv[j] - bf2f(hb));
    }
  }
  const int kr = t >> 2;
  const int qd = t & 3;
  float m_r[4], l_r[4];
#pragma unroll
  for (int r = 0; r < 4; ++r) { m_r[r] = -INFINITY; l_r[r] = 0.0f; }
  f32x4 o_acc[4];
#pragma unroll
  for (int c = 0; c < 4; ++c) o_acc[c] = (f32x4){0.f, 0.f, 0.f, 0.f};
  const uint32_t rowlin = ((uint32_t)(b * Hn + h)) * (uint32_t)Sn +
                          (uint32_t)(qbase + w * 16 + quad * 4);
  for (int kt = 0; kt < Sn / 64; ++kt) {
    const int kbase = kt * 64;
    __syncthreads();
    {
      const float* ksrc = Kp + (size_t)(kbase + kr) * Dn + qd * 16;
#pragma unroll
      for (int half = 0; half < 2; ++half) {
        float4 a = *(const float4*)(ksrc + half * 8);
        float4 b2 = *(const float4*)(ksrc + half * 8 + 4);
        float xs[8] = {a.x, a.y, a.z, a.w, b2.x, b2.y, b2.z, b2.w};
        s16x8 hv, lv;
#pragma unroll
        for (int j = 0; j < 8; ++j) {
          uint16_t hb = f2bf(xs[j]);
          hv[j] = (short)hb;
          lv[j] = (short)f2bf(xs[j] - bf2f(hb));
        }
        *(s16x8*)&KhS[kr * KST + qd * 16 + half * 8] = hv;
        *(s16x8*)&KlS[kr * KST + qd * 16 + half * 8] = lv;
      }
      const float* vsrc = Vp + (size_t)(kbase + kr) * Dn + qd * 16;
#pragma unroll
      for (int half = 0; half < 2; ++half) {
        float4 a = *(const float4*)(vsrc + half * 8);
        float4 b2 = *(const float4*)(vsrc + half * 8 + 4);
        float xs[8] = {a.x, a.y, a.z, a.w, b2.x, b2.y, b2.z, b2.w};
#pragma unroll
        for (int j = 0; j < 8; ++j)
          VtS[(qd * 16 + half * 8 + j) * KST + kr] = f2bf(xs[j]);
      }
    }
    __syncthreads();
    f32x4 sacc[4];
#pragma unroll
    for (int c = 0; c < 4; ++c) sacc[c] = (f32x4){0.f, 0.f, 0.f, 0.f};
#pragma unroll
    for (int ks = 0; ks < 2; ++ks) {
#pragma unroll
      for (int c = 0; c < 4; ++c) {
        const s16x8 bh_ = *(const s16x8*)&KhS[(c * 16 + l16) * KST + ks * 32 + quad * 8];
        const s16x8 bl_ = *(const s16x8*)&KlS[(c * 16 + l16) * KST + ks * 32 + quad * 8];
        sacc[c] = __builtin_amdgcn_mfma_f32_16x16x32_bf16(qh[ks], bh_, sacc[c], 0, 0, 0);
        sacc[c] = __builtin_amdgcn_mfma_f32_16x16x32_bf16(ql[ks], bh_, sacc[c], 0, 0, 0);
        sacc[c] = __builtin_amdgcn_mfma_f32_16x16x32_bf16(qh[ks], bl_, sacc[c], 0, 0, 0);
      }
    }
    float mx[4];
#pragma unroll
    for (int r = 0; r < 4; ++r) {
      mx[r] = sacc[0][r] * scale;
#pragma unroll
      for (int c = 1; c < 4; ++c) mx[r] = fmaxf(mx[r], sacc[c][r] * scale);
#pragma unroll
      for (int d = 1; d < 16; d <<= 1) mx[r] = fmaxf(mx[r], __shfl_xor(mx[r], d));
    }
    float al[4];
#pragma unroll
    for (int r = 0; r < 4; ++r) {
      const float mn = fmaxf(m_r[r], mx[r]);
      al[r] = __expf(m_r[r] - mn);
      m_r[r] = mn;
    }
#pragma unroll
    for (int c = 0; c < 4; ++c)
#pragma unroll
      for (int r = 0; r < 4; ++r) o_acc[c][r] *= al[r];
    float rs[4] = {0.f, 0.f, 0.f, 0.f};
#pragma unroll
    for (int c = 0; c < 4; ++c) {
#pragma unroll
      for (int r = 0; r < 4; ++r) {
        const float d = sacc[c][r] * scale - m_r[r];
        float pv = __expf(d);
        rs[r] += pv;
        if (d > -25.0f) {
          const uint32_t j = (rowlin + (uint32_t)r) * (uint32_t)Sn +
                             (uint32_t)(kbase + c * 16 + l16);
          if (!keep_bit(j)) pv = 0.0f;
        }
        PSf[(w * 16 + quad * 4 + r) * KST + c * 16 + l16] = f2bf(pv);
      }
    }
#pragma unroll
    for (int r = 0; r < 4; ++r) {
#pragma unroll
      for (int d = 1; d < 16; d <<= 1) rs[r] += __shfl_xor(rs[r], d);
      l_r[r] = l_r[r] * al[r] + rs[r];
    }
#pragma unroll
    for (int ks2 = 0; ks2 < 2; ++ks2) {
      const s16x8 pa = *(const s16x8*)&PSf[(w * 16 + l16) * KST + ks2 * 32 + quad * 8];
#pragma unroll
      for (int c = 0; c < 4; ++c) {
        const s16x8 vb = *(const s16x8*)&VtS[(c * 16 + l16) * KST + ks2 * 32 + quad * 8];
        o_acc[c] = __builtin_amdgcn_mfma_f32_16x16x32_bf16(pa, vb, o_acc[c], 0, 0, 0);
      }
    }
  }
  float inv[4];
#pragma unroll
  for (int r = 0; r < 4; ++r) inv[r] = 1.0f / (l_r[r] * 0.9f);
#pragma unroll
  for (int c = 0; c < 4; ++c)
#pragma unroll
    for (int r = 0; r < 4; ++r)
      out[(bh * Sn + (size_t)(qbase + w * 16 + quad * 4 + r)) * Dn + c * 16 + l16] =
          o_acc[c][r] * inv[r];
}

extern "C" void kernel_launch(void* const* d_in, const int* in_sizes, int n_in,
                              void* d_out, int out_size, void* d_ws, size_t ws_size,
                              hipStream_t stream) {
  const float* Q = (const float*)d_in[0];
  const float* K = (const float*)d_in[1];
  const float* V = (const float*)d_in[2];
  const int* sf = (const int*)d_in[3];
  float* out = (float*)d_out;

  constexpr size_t ARR = (size_t)Bn * Hn * Sn * Dn;  // 4,194,304 elems (8 MB bf16)
  const size_t need = 3 * ARR * sizeof(uint16_t);    // 24 MB

  if (ws_size >= need) {
    uint16_t* Khg = (uint16_t*)d_ws;
    uint16_t* Klg = Khg + ARR;
    uint16_t* Vtg = Klg + ARR;
    prep_kv<<<dim3(16, 64), NTF, 0, stream>>>(K, V, Khg, Klg, Vtg);
    attn_mfma7<<<dim3(Sn / TQM, Hn, Bn), NT, 0, stream>>>(Q, Khg, Klg, Vtg, V, sf, out);
  } else {
    attn_fallback<<<dim3(Sn / 64, Hn, Bn), NTF, 0, stream>>>(Q, K, V, sf, out);
  }
}

// Round 8
// 160.742 us; speedup vs baseline: 1.0690x; 1.0100x over previous
//
#include <hip/hip_runtime.h>
#include <hip/hip_bf16.h>
#include <stdint.h>
#include <math.h>

// Attention: out = dropout(softmax(8 * Q K^T)) V, B=4 H=16 S=1024 D=64 fp32.
// R17 = R16 + T1 XCD-aware work permutation + T5 setprio (both zero-sync-risk).
//  - T1: R16's FETCH stayed 110MB (ideal 40MB): q-blocks sharing a bh's K/V
//    tiles were spread across all 8 XCDs (XCD = linear%8 = blockIdx.x = qb),
//    so every XCD's L2 re-fetched every tile. Remap (x,y,z) -> (bh,qb):
//    bh = x*8+(y&7), qb = (y>>3)*4+z  [bijective]. All 8 q-blocks of a bh
//    now land on ONE XCD; per-XCD ws footprint 8 bh x 384KB = 3MB <= 4MB L2
//    -> staging becomes L2-hit (~200cy vs ~600-900cy) -> prefetch fully
//    hidden under the ~2.5K-cycle tile compute.
//  - T5: s_setprio(1) around QK/PV MFMA clusters (m191: +4-7% attn).
//  - R16 structure unchanged: ping-pong dbuf, ONE barrier per tile, NT=512,
//    TQM=128, 2 blocks/CU x 8 waves. Prefetch never writes a buffer read in
//    the current barrier interval (R10 lesson).
//  - Numerics diet (bisect-PROVEN safe, absmax 0.03125): native RNE cvts,
//    log2-domain softmax (exp2), defer-rescale.
//  - S^T = K Q^T: C-layout col = q -> per-lane softmax state, 2 shuffles/row.
//  - Dropout: deferred correction (candidate list + dense threefry drain).
//    Threefry: counter-mode, bits = y0^y1 (VERIFIED R2); threshold exp(-11).

constexpr int Bn = 4, Hn = 16, Sn = 1024, Dn = 64;
constexpr int NT = 512;   // main kernel: 8 waves/block
constexpr int NTF = 256;  // prep + fallback block size
constexpr int TK = 64;
constexpr int TQM = 128;  // q rows per block (wave w owns rows w*16..w*16+15)
constexpr int CAP = 128;  // per-wave candidate list capacity (overflow path exact)
constexpr int NTILE = Sn / TK;  // 16

typedef short s16x8 __attribute__((ext_vector_type(8)));
typedef short s16x4 __attribute__((ext_vector_type(4)));
typedef float f32x4 __attribute__((ext_vector_type(4)));

__device__ __forceinline__ uint16_t f2bf(float x) {  // RNE float->bf16 (manual)
  uint32_t u = __float_as_uint(x);
  return (uint16_t)((u + 0x7fffu + ((u >> 16) & 1u)) >> 16);
}
__device__ __forceinline__ uint16_t f2bf_fast(float x) {  // RNE via v_cvt (fusable)
  return __builtin_bit_cast(uint16_t, __float2bfloat16(x));
}
__device__ __forceinline__ float bf2f(uint16_t h) {
  return __uint_as_float(((uint32_t)h) << 16);
}
__device__ __forceinline__ float fexp2(float x) {  // v_exp_f32 (2^x)
  return __builtin_amdgcn_exp2f(x);
}

__device__ __forceinline__ void tf_round(uint32_t& x0, uint32_t& x1, const int r) {
  x0 += x1;
  x1 = (x1 << r) | (x1 >> (32 - r));
  x1 ^= x0;
}

// threefry2x32, key(42)=(0,42), counter (0, j), bits = y0^y1  [VERIFIED R2]
__device__ __noinline__ int keep_bit(uint32_t j) {
  uint32_t x0 = 0u, x1 = j;
  const uint32_t k0 = 0u, k1v = 42u;
  const uint32_t k2v = k0 ^ k1v ^ 0x1BD11BDAu;
  x0 += k0; x1 += k1v;
  tf_round(x0, x1, 13); tf_round(x0, x1, 15); tf_round(x0, x1, 26); tf_round(x0, x1, 6);
  x0 += k1v; x1 += k2v + 1u;
  tf_round(x0, x1, 17); tf_round(x0, x1, 29); tf_round(x0, x1, 16); tf_round(x0, x1, 24);
  x0 += k2v; x1 += k0 + 2u;
  tf_round(x0, x1, 13); tf_round(x0, x1, 15); tf_round(x0, x1, 26); tf_round(x0, x1, 6);
  x0 += k0; x1 += k1v + 3u;
  tf_round(x0, x1, 17); tf_round(x0, x1, 29); tf_round(x0, x1, 16); tf_round(x0, x1, 24);
  x0 += k1v; x1 += k2v + 4u;
  tf_round(x0, x1, 13); tf_round(x0, x1, 15); tf_round(x0, x1, 26); tf_round(x0, x1, 6);
  x0 += k2v; x1 += k0 + 5u;
  uint32_t bits = x0 ^ x1;
  float u = __uint_as_float((bits >> 9) | 0x3f800000u) - 1.0f;
  return u < 0.9f;
}

// ---------------- pre-pass: K split + V transpose, swizzled bf16 tiles ----------------
__global__ __launch_bounds__(NTF) void prep_kv(const float* __restrict__ K,
                                               const float* __restrict__ V,
                                               uint16_t* __restrict__ Khg,
                                               uint16_t* __restrict__ Klg,
                                               uint16_t* __restrict__ Vtg) {
  __shared__ float Vl[TK][Dn + 1];
  const int t = threadIdx.x;
  const int kt = blockIdx.x;   // 0..15
  const int bh = blockIdx.y;   // 0..63
  const int r = t >> 2, qd = t & 3;
  const size_t tile = ((size_t)bh * 16 + kt) * 4096;
  const float* ksrc = K + ((size_t)bh * Sn + (size_t)(kt * TK + r)) * Dn + qd * 16;
  const float* vsrc = V + ((size_t)bh * Sn + (size_t)(kt * TK + r)) * Dn + qd * 16;

#pragma unroll
  for (int half = 0; half < 2; ++half) {
    float4 a = *(const float4*)(ksrc + half * 8);
    float4 b = *(const float4*)(ksrc + half * 8 + 4);
    float xs[8] = {a.x, a.y, a.z, a.w, b.x, b.y, b.z, b.w};
    s16x8 hv, lv;
#pragma unroll
    for (int j = 0; j < 8; ++j) {
      uint16_t hb = f2bf(xs[j]);
      hv[j] = (short)hb;
      lv[j] = (short)f2bf(xs[j] - bf2f(hb));
    }
    const int sc = (qd * 2 + half) ^ (r & 7);
    *(s16x8*)&Khg[tile + (size_t)r * 64 + sc * 8] = hv;
    *(s16x8*)&Klg[tile + (size_t)r * 64 + sc * 8] = lv;
    float4 va = *(const float4*)(vsrc + half * 8);
    float4 vb = *(const float4*)(vsrc + half * 8 + 4);
    *(float4*)&Vl[r][qd * 16 + half * 8] = va;
    *(float4*)&Vl[r][qd * 16 + half * 8 + 4] = vb;
  }
  __syncthreads();
#pragma unroll
  for (int half = 0; half < 2; ++half) {
    s16x8 ov;
#pragma unroll
    for (int j = 0; j < 8; ++j) ov[j] = (short)f2bf(Vl[qd * 16 + half * 8 + j][r]);
    const int sc = (qd * 2 + half) ^ (r & 7);
    *(s16x8*)&Vtg[tile + (size_t)r * 64 + sc * 8] = ov;
  }
}

// -------- main flash kernel: S^T orientation, TQ=128, 8 waves, dbuf ping-pong --------
__global__ __launch_bounds__(NT, 4) void attn_mfma7(
    const float* __restrict__ Q, const uint16_t* __restrict__ Khg,
    const uint16_t* __restrict__ Klg, const uint16_t* __restrict__ Vtg,
    const float* __restrict__ V, const int* __restrict__ scale_ptr,
    float* __restrict__ out) {
  __shared__ uint16_t KhS[2][TK * Dn];   // 2 x 8 KB ping-pong (DMA dest, swizzled)
  __shared__ uint16_t KlS[2][TK * Dn];
  __shared__ uint16_t VtS[2][TK * Dn];
  __shared__ uint16_t PS[8 * 16 * 64];   // per-wave P[q][key], XOR-chunk swizzled
  __shared__ uint32_t Lm[8][CAP];        // per-wave candidate list: (rw<<10)|key
  __shared__ float Lsv[8][CAP];          // candidate raw logit s (log2 domain)
  __shared__ float mfin[8][16];          // per-wave final row max (log2 domain)

  const int t = threadIdx.x;
  const int w = t >> 6;                  // 0..7
  const int lane = t & 63;
  const int l16 = lane & 15;
  const int quad = lane >> 4;
  const int xl = l16 & 7;                // XOR swizzle key

  // ---- T1: XCD-aware work permutation. Grid (8,16,4); XCD = linear%8 = x.
  // bh = x*8+(y&7), qb = (y>>3)*4+z  [bijective]: all 8 q-blocks of one bh
  // land on one XCD -> per-XCD ws footprint 3MB fits its 4MB L2. ----
  const int bh = blockIdx.x * 8 + (blockIdx.y & 7);
  const int qb = ((blockIdx.y >> 3) << 2) | blockIdx.z;
  const int qbase = qb * TQM;
  // log2(e) folded into the Q pre-scale: all logits live in the log2 domain.
  const float qscale = (float)(*scale_ptr) * 1.44269504089f;
  const float pthr = 1.670170079e-5f;    // exp(-11), in the p domain (unchanged)

  // per-wave DMA segment: wave w covers elements [w*512, w*512+512) of each tile
  const int eoff = w * 512 + lane * 8;
  const size_t tbase = (size_t)bh * 16 * 4096;
  const int psw = w * 1024;              // per-wave PS base (elements)

  auto issue3 = [&](int ti, int pb) {    // stage Kh,Kl,Vt of tile ti into buf pb
    const size_t tile = tbase + (size_t)ti * 4096;
    __builtin_amdgcn_global_load_lds(
        (const __attribute__((address_space(1))) uint32_t*)(Khg + tile + eoff),
        (__attribute__((address_space(3))) uint32_t*)(&KhS[pb][eoff]), 16, 0, 0);
    __builtin_amdgcn_global_load_lds(
        (const __attribute__((address_space(1))) uint32_t*)(Klg + tile + eoff),
        (__attribute__((address_space(3))) uint32_t*)(&KlS[pb][eoff]), 16, 0, 0);
    __builtin_amdgcn_global_load_lds(
        (const __attribute__((address_space(1))) uint32_t*)(Vtg + tile + eoff),
        (__attribute__((address_space(3))) uint32_t*)(&VtS[pb][eoff]), 16, 0, 0);
  };

  // prologue: tile 0 -> buf0 in flight; Q load/split overlaps it
  issue3(0, 0);

  // ---- Q B-frags (pre-scaled, log2 domain): wave w owns q rows qbase+w*16+l16 ----
  s16x8 qh[2], ql[2];
  {
    const int qrow = qbase + w * 16 + l16;
    const float* src = Q + ((size_t)bh * Sn + (size_t)qrow) * Dn;
#pragma unroll
    for (int ks = 0; ks < 2; ++ks) {
      float4 x0 = *(const float4*)(src + ks * 32 + quad * 8);
      float4 x1 = *(const float4*)(src + ks * 32 + quad * 8 + 4);
      float xv[8] = {x0.x, x0.y, x0.z, x0.w, x1.x, x1.y, x1.z, x1.w};
#pragma unroll
      for (int j = 0; j < 8; ++j) {
        const float xs = xv[j] * qscale;
        uint16_t hb = f2bf_fast(xs);
        qh[ks][j] = (short)hb;
        ql[ks][j] = (short)f2bf_fast(xs - bf2f(hb));
      }
    }
  }

  // per-lane softmax state: ONE q per lane (log2 domain)
  float m_r = -INFINITY, l_r = 0.0f;
  // O^T accumulator: o_acc[c][r] = O[q = l16][dv = c*16+quad*4+r]
  f32x4 o_acc[4];
#pragma unroll
  for (int c = 0; c < 4; ++c) o_acc[c] = (f32x4){0.f, 0.f, 0.f, 0.f};

  const uint32_t hbase = (uint32_t)bh * (uint32_t)Sn;
  int lbase = 0;  // per-wave list fill (wave-uniform)

  // one tile's QK -> softmax -> PV, reading buffers [pb]
  auto tile_step = [&](int kbase, int pb) {
    // ---- S^T = K Q^T: A = K tile (LDS), B = Q (regs), split-bf16 3-MFMA ----
    f32x4 sacc[4];
#pragma unroll
    for (int c = 0; c < 4; ++c) sacc[c] = (f32x4){0.f, 0.f, 0.f, 0.f};
    __builtin_amdgcn_s_setprio(1);     // T5: favor MFMA cluster
#pragma unroll
    for (int ks = 0; ks < 2; ++ks) {
#pragma unroll
      for (int c = 0; c < 4; ++c) {
        const int boff = (c * 16 + l16) * 64 + (((ks * 4 + quad) ^ xl) * 8);
        const s16x8 khv = *(const s16x8*)&KhS[pb][boff];
        const s16x8 klv = *(const s16x8*)&KlS[pb][boff];
        sacc[c] = __builtin_amdgcn_mfma_f32_16x16x32_bf16(khv, qh[ks], sacc[c], 0, 0, 0);
        sacc[c] = __builtin_amdgcn_mfma_f32_16x16x32_bf16(khv, ql[ks], sacc[c], 0, 0, 0);
        sacc[c] = __builtin_amdgcn_mfma_f32_16x16x32_bf16(klv, qh[ks], sacc[c], 0, 0, 0);
      }
    }
    __builtin_amdgcn_s_setprio(0);

    // ---- online softmax (per-lane row state), fused push + P store ----
    {
      float mx = sacc[0][0];
#pragma unroll
      for (int c = 0; c < 4; ++c)
#pragma unroll
        for (int r = 0; r < 4; ++r) mx = fmaxf(mx, sacc[c][r]);
      mx = fmaxf(mx, __shfl_xor(mx, 16));
      mx = fmaxf(mx, __shfl_xor(mx, 32));  // row max over all 64 keys of tile

      // defer-rescale: if no lane's max grew, alpha==1 exactly -> skip the pass
      if (__ballot(mx > m_r) != 0ull) {
        const float mn = fmaxf(m_r, mx);
        const float al = fexp2(m_r - mn);  // 0 on first tile
        m_r = mn;
#pragma unroll
        for (int c = 0; c < 4; ++c)
#pragma unroll
          for (int r = 0; r < 4; ++r) o_acc[c][r] *= al;
        l_r *= al;
      }

      // -15.88 < -11*log2(e): gate true whenever any pc can exceed pthr
      const bool anyhot = __ballot(mx - m_r > -15.88f) != 0ull;
      float rs = 0.0f;
#pragma unroll
      for (int c = 0; c < 4; ++c) {
        float pc[4];  // only 4 floats live at the pressure peak (reg diet)
#pragma unroll
        for (int r = 0; r < 4; ++r) {
          pc[r] = fexp2(sacc[c][r] - m_r);
          rs += pc[r];  // UNMASKED row sum (softmax normalizes before dropout)
        }
        if (anyhot) {
#pragma unroll
          for (int r = 0; r < 4; ++r) {
            const uint64_t mc = __ballot(pc[r] > pthr);
            if (mc != 0ull) {
              if (lbase + 64 <= CAP) {
                const int slot = lbase + (int)__popcll(mc & ((1ull << lane) - 1ull));
                if (pc[r] > pthr) {
                  Lm[w][slot] = ((uint32_t)l16 << 10) |
                                (uint32_t)(kbase + c * 16 + quad * 4 + r);
                  Lsv[w][slot] = sacc[c][r];  // raw logit (log2 domain)
                }
                lbase += (int)__popcll(mc);
              } else if (pc[r] > pthr) {  // overflow: inline exact dropout
                const uint32_t j =
                    (hbase + (uint32_t)(qbase + w * 16 + l16)) * (uint32_t)Sn +
                    (uint32_t)(kbase + c * 16 + quad * 4 + r);
                if (!keep_bit(j)) pc[r] = 0.0f;  // rs already added (unmasked)
              }
            }
          }
        }
        // P store: 4 consecutive keys -> b64, XOR-chunk swizzled (native cvt)
        s16x4 pk;
#pragma unroll
        for (int r = 0; r < 4; ++r) pk[r] = (short)f2bf_fast(pc[r]);
        const int pos = (c * 2 + (quad >> 1)) ^ xl;
        *(s16x4*)&PS[psw + l16 * 64 + pos * 8 + (quad & 1) * 4] = pk;
      }

      rs += __shfl_xor(rs, 16);
      rs += __shfl_xor(rs, 32);
      l_r += rs;
    }

    // ---- PV as O^T: A = Vt (LDS), B = P (LDS, same-wave RAW) ----
    __builtin_amdgcn_s_setprio(1);     // T5
#pragma unroll
    for (int ks2 = 0; ks2 < 2; ++ks2) {
      const s16x8 pfr = *(const s16x8*)&PS[psw + l16 * 64 + (((ks2 * 4 + quad) ^ xl) * 8)];
#pragma unroll
      for (int c = 0; c < 4; ++c) {
        const int voff = (c * 16 + l16) * 64 + (((ks2 * 4 + quad) ^ xl) * 8);
        const s16x8 vb = *(const s16x8*)&VtS[pb][voff];
        o_acc[c] = __builtin_amdgcn_mfma_f32_16x16x32_bf16(vb, pfr, o_acc[c], 0, 0, 0);
      }
    }
    __builtin_amdgcn_s_setprio(0);
  };

  // ---- ping-pong main loop: ONE barrier per tile, prefetch into other buffer ----
  for (int kt = 0; kt < NTILE; kt += 2) {
    __syncthreads();               // own vmcnt(0) drained -> buf0(kt) visible to all;
                                   // all waves done reading buf1 (tile kt-1)
    issue3(kt + 1, 1);             // kt+1 <= 15 always (NTILE even)
    tile_step(kt * TK, 0);
    __syncthreads();               // buf1(kt+1) visible; all done reading buf0(kt)
    if (kt + 2 < NTILE) issue3(kt + 2, 0);
    tile_step((kt + 1) * TK, 1);
  }

  // ---- drain: dense threefry over candidate list, subtract dropped p*V ----
  if (quad == 0) mfin[w][l16] = m_r;
  for (int e0 = 0; e0 < lbase; e0 += 64) {
    const int e = e0 + lane;
    const bool valid = e < lbase;
    const uint32_t meta = valid ? Lm[w][e] : 0u;
    const float sv = valid ? Lsv[w][e] : 0.0f;
    const uint32_t rwv = meta >> 10, keyv = meta & 1023u;
    const uint32_t grow = (uint32_t)(qbase + w * 16) + rwv;
    const uint32_t j = (hbase + grow) * (uint32_t)Sn + keyv;
    const int kb = keep_bit(j);  // dense: all 64 lanes productive
    uint64_t dm = __ballot(valid && !kb);
    while (dm != 0ull) {
      const int src = (int)__builtin_ctzll(dm);
      dm &= dm - 1ull;
      const uint32_t meta_s = (uint32_t)__builtin_amdgcn_readlane((int)meta, src);
      const float sv_s =
          __uint_as_float((uint32_t)__builtin_amdgcn_readlane((int)__float_as_uint(sv), src));
      const int rw = (int)(meta_s >> 10);
      const int key = (int)(meta_s & 1023u);
      const float p = fexp2(sv_s - mfin[w][rw]);   // log2 domain
      const float pb2 = bf2f(f2bf_fast(p));        // matches stored bf16(P) bits
      if (rw == l16) {  // the 4 quads owning column q participate
        const float* vp = V + ((size_t)bh * Sn + (size_t)key) * Dn;
#pragma unroll
        for (int c = 0; c < 4; ++c) {
          float4 vv = *(const float4*)(vp + c * 16 + quad * 4);
          o_acc[c][0] = fmaf(-pb2, bf2f(f2bf(vv.x)), o_acc[c][0]);
          o_acc[c][1] = fmaf(-pb2, bf2f(f2bf(vv.y)), o_acc[c][1]);
          o_acc[c][2] = fmaf(-pb2, bf2f(f2bf(vv.z)), o_acc[c][2]);
          o_acc[c][3] = fmaf(-pb2, bf2f(f2bf(vv.w)), o_acc[c][3]);
        }
      }
    }
  }

  // ---- epilogue: out[q][dv] = O^T / (l * 0.9); per-lane scalar scale ----
  {
    const float inv = 1.0f / (l_r * 0.9f);
    const size_t obase = ((size_t)bh * Sn + (size_t)(qbase + w * 16 + l16)) * Dn;
#pragma unroll
    for (int c = 0; c < 4; ++c) {
      float4 ov;
      ov.x = o_acc[c][0] * inv;
      ov.y = o_acc[c][1] * inv;
      ov.z = o_acc[c][2] * inv;
      ov.w = o_acc[c][3] * inv;
      *(float4*)(out + obase + c * 16 + quad * 4) = ov;
    }
  }
}

// ---------------- fallback (R3 kernel, verbatim): used only if ws too small ----------------
constexpr int KST = 72;
__global__ __launch_bounds__(NTF) void attn_fallback(
    const float* __restrict__ Q, const float* __restrict__ K,
    const float* __restrict__ V, const int* __restrict__ scale_ptr,
    float* __restrict__ out) {
  __shared__ uint16_t KhS[64 * KST];
  __shared__ uint16_t KlS[64 * KST];
  __shared__ uint16_t VtS[Dn * KST];
  __shared__ uint16_t PSf[4 * 16 * KST];

  const int t = threadIdx.x;
  const int w = t >> 6;
  const int lane = t & 63;
  const int l16 = lane & 15;
  const int quad = lane >> 4;
  const int b = blockIdx.z, h = blockIdx.y;
  const int qbase = blockIdx.x * 64;
  const size_t bh = (size_t)b * Hn + h;
  const float scale = (float)(*scale_ptr);
  const float* Kp = K + bh * Sn * Dn;
  const float* Vp = V + bh * Sn * Dn;

  const int qrow = qbase + w * 16 + l16;
  const float* Qp = Q + (bh * Sn + (size_t)qrow) * Dn;
  s16x8 qh[2], ql[2];
#pragma unroll
  for (int ks = 0; ks < 2; ++ks) {
    const float* src = Qp + ks * 32 + quad * 8;
    float4 x0 = *(const float4*)(src);
    float4 x1 = *(const float4*)(src + 4);
    float xv[8] = {x0.x, x0.y, x0.z, x0.w, x1.x, x1.y, x1.z, x1.w};
#pragma unroll
    for (int j = 0; j < 8; ++j) {
      uint16_t hb = f2bf(xv[j]);
      qh[ks][j] = (short)hb;
      ql[ks][j] = (short)f2bf(xv[j] - bf2f(hb));
    }
  }
  const int kr = t >> 2;
  const int qd = t & 3;
  float m_r[4], l_r[4];
#pragma unroll
  for (int r = 0; r < 4; ++r) { m_r[r] = -INFINITY; l_r[r] = 0.0f; }
  f32x4 o_acc[4];
#pragma unroll
  for (int c = 0; c < 4; ++c) o_acc[c] = (f32x4){0.f, 0.f, 0.f, 0.f};
  const uint32_t rowlin = ((uint32_t)(b * Hn + h)) * (uint32_t)Sn +
                          (uint32_t)(qbase + w * 16 + quad * 4);
  for (int kt = 0; kt < Sn / 64; ++kt) {
    const int kbase = kt * 64;
    __syncthreads();
    {
      const float* ksrc = Kp + (size_t)(kbase + kr) * Dn + qd * 16;
#pragma unroll
      for (int half = 0; half < 2; ++half) {
        float4 a = *(const float4*)(ksrc + half * 8);
        float4 b2 = *(const float4*)(ksrc + half * 8 + 4);
        float xs[8] = {a.x, a.y, a.z, a.w, b2.x, b2.y, b2.z, b2.w};
        s16x8 hv, lv;
#pragma unroll
        for (int j = 0; j < 8; ++j) {
          uint16_t hb = f2bf(xs[j]);
          hv[j] = (short)hb;
          lv[j] = (short)f2bf(xs[j] - bf2f(hb));
        }
        *(s16x8*)&KhS[kr * KST + qd * 16 + half * 8] = hv;
        *(s16x8*)&KlS[kr * KST + qd * 16 + half * 8] = lv;
      }
      const float* vsrc = Vp + (size_t)(kbase + kr) * Dn + qd * 16;
#pragma unroll
      for (int half = 0; half < 2; ++half) {
        float4 a = *(const float4*)(vsrc + half * 8);
        float4 b2 = *(const float4*)(vsrc + half * 8 + 4);
        float xs[8] = {a.x, a.y, a.z, a.w, b2.x, b2.y, b2.z, b2.w};
#pragma unroll
        for (int j = 0; j < 8; ++j)
          VtS[(qd * 16 + half * 8 + j) * KST + kr] = f2bf(xs[j]);
      }
    }
    __syncthreads();
    f32x4 sacc[4];
#pragma unroll
    for (int c = 0; c < 4; ++c) sacc[c] = (f32x4){0.f, 0.f, 0.f, 0.f};
#pragma unroll
    for (int ks = 0; ks < 2; ++ks) {
#pragma unroll
      for (int c = 0; c < 4; ++c) {
        const s16x8 bh_ = *(const s16x8*)&KhS[(c * 16 + l16) * KST + ks * 32 + quad * 8];
        const s16x8 bl_ = *(const s16x8*)&KlS[(c * 16 + l16) * KST + ks * 32 + quad * 8];
        sacc[c] = __builtin_amdgcn_mfma_f32_16x16x32_bf16(qh[ks], bh_, sacc[c], 0, 0, 0);
        sacc[c] = __builtin_amdgcn_mfma_f32_16x16x32_bf16(ql[ks], bh_, sacc[c], 0, 0, 0);
        sacc[c] = __builtin_amdgcn_mfma_f32_16x16x32_bf16(qh[ks], bl_, sacc[c], 0, 0, 0);
      }
    }
    float mx[4];
#pragma unroll
    for (int r = 0; r < 4; ++r) {
      mx[r] = sacc[0][r] * scale;
#pragma unroll
      for (int c = 1; c < 4; ++c) mx[r] = fmaxf(mx[r], sacc[c][r] * scale);
#pragma unroll
      for (int d = 1; d < 16; d <<= 1) mx[r] = fmaxf(mx[r], __shfl_xor(mx[r], d));
    }
    float al[4];
#pragma unroll
    for (int r = 0; r < 4; ++r) {
      const float mn = fmaxf(m_r[r], mx[r]);
      al[r] = __expf(m_r[r] - mn);
      m_r[r] = mn;
    }
#pragma unroll
    for (int c = 0; c < 4; ++c)
#pragma unroll
      for (int r = 0; r < 4; ++r) o_acc[c][r] *= al[r];
    float rs[4] = {0.f, 0.f, 0.f, 0.f};
#pragma unroll
    for (int c = 0; c < 4; ++c) {
#pragma unroll
      for (int r = 0; r < 4; ++r) {
        const float d = sacc[c][r] * scale - m_r[r];
        float pv = __expf(d);
        rs[r] += pv;
        if (d > -25.0f) {
          const uint32_t j = (rowlin + (uint32_t)r) * (uint32_t)Sn +
                             (uint32_t)(kbase + c * 16 + l16);
          if (!keep_bit(j)) pv = 0.0f;
        }
        PSf[(w * 16 + quad * 4 + r) * KST + c * 16 + l16] = f2bf(pv);
      }
    }
#pragma unroll
    for (int r = 0; r < 4; ++r) {
#pragma unroll
      for (int d = 1; d < 16; d <<= 1) rs[r] += __shfl_xor(rs[r], d);
      l_r[r] = l_r[r] * al[r] + rs[r];
    }
#pragma unroll
    for (int ks2 = 0; ks2 < 2; ++ks2) {
      const s16x8 pa = *(const s16x8*)&PSf[(w * 16 + l16) * KST + ks2 * 32 + quad * 8];
#pragma unroll
      for (int c = 0; c < 4; ++c) {
        const s16x8 vb = *(const s16x8*)&VtS[(c * 16 + l16) * KST + ks2 * 32 + quad * 8];
        o_acc[c] = __builtin_amdgcn_mfma_f32_16x16x32_bf16(pa, vb, o_acc[c], 0, 0, 0);
      }
    }
  }
  float inv[4];
#pragma unroll
  for (int r = 0; r < 4; ++r) inv[r] = 1.0f / (l_r[r] * 0.9f);
#pragma unroll
  for (int c = 0; c < 4; ++c)
#pragma unroll
    for (int r = 0; r < 4; ++r)
      out[(bh * Sn + (size_t)(qbase + w * 16 + quad * 4 + r)) * Dn + c * 16 + l16] =
          o_acc[c][r] * inv[r];
}

extern "C" void kernel_launch(void* const* d_in, const int* in_sizes, int n_in,
                              void* d_out, int out_size, void* d_ws, size_t ws_size,
                              hipStream_t stream) {
  const float* Q = (const float*)d_in[0];
  const float* K = (const float*)d_in[1];
  const float* V = (const float*)d_in[2];
  const int* sf = (const int*)d_in[3];
  float* out = (float*)d_out;

  constexpr size_t ARR = (size_t)Bn * Hn * Sn * Dn;  // 4,194,304 elems (8 MB bf16)
  const size_t need = 3 * ARR * sizeof(uint16_t);    // 24 MB

  if (ws_size >= need) {
    uint16_t* Khg = (uint16_t*)d_ws;
    uint16_t* Klg = Khg + ARR;
    uint16_t* Vtg = Klg + ARR;
    prep_kv<<<dim3(16, 64), NTF, 0, stream>>>(K, V, Khg, Klg, Vtg);
    attn_mfma7<<<dim3(Sn / TQM, Hn, Bn), NT, 0, stream>>>(Q, Khg, Klg, Vtg, V, sf, out);
  } else {
    attn_fallback<<<dim3(Sn / 64, Hn, Bn), NTF, 0, stream>>>(Q, K, V, sf, out);
  }
}

// Round 10
// 160.519 us; speedup vs baseline: 1.0705x; 1.0014x over previous
//
#include <hip/hip_runtime.h>
#include <hip/hip_bf16.h>
#include <stdint.h>
#include <math.h>

// Attention: out = dropout(softmax(8 * Q K^T)) V, B=4 H=16 S=1024 D=64 fp32.
// R19 = R18 resubmitted verbatim (R18 hit "MI355X container failed twice" —
// broker-level, pre-compile; precedent R11/R12->R13 and R15->R16: identical
// source passed after the same error). attn_mfma7 UNTOUCHED (proven 79us,
// FETCH 22.5MB) + prep_kv rewritten for full coalescing. PROBE: total-vs-attn
// gap is a constant ~81us across all rounds (169.6-89.1, 167.9-86.4,
// 162.3-81.2, 160.7-79.0) and prep_kv never shows in top-5 — it is either
// prep_kv (fixable) or harness overhead (not).
// Old prep: 4-lane groups strided 64B apart (~50% line util), 64B partial-line
// scatter stores. New prep: wave reads 8 complete rows = 2KB contiguous;
// 8 lanes complete each 128B output line in XOR-permuted 16B chunks.
// Output bytes IDENTICAL (RNE cvt bit-identical, sc = chunk^(r&7) unchanged,
// V-transpose phase verbatim) -> absmax must stay 0.03125.
// attn side (R17, proven): T1 XCD permutation (FETCH 110->22.5MB), T5 setprio,
// ping-pong dbuf ONE barrier/tile, NT=512 TQM=128, numerics diet, S^T=K Q^T,
// deferred-correction dropout (threefry VERIFIED R2).

constexpr int Bn = 4, Hn = 16, Sn = 1024, Dn = 64;
constexpr int NT = 512;   // main kernel: 8 waves/block
constexpr int NTF = 256;  // prep + fallback block size
constexpr int TK = 64;
constexpr int TQM = 128;  // q rows per block (wave w owns rows w*16..w*16+15)
constexpr int CAP = 128;  // per-wave candidate list capacity (overflow path exact)
constexpr int NTILE = Sn / TK;  // 16

typedef short s16x8 __attribute__((ext_vector_type(8)));
typedef short s16x4 __attribute__((ext_vector_type(4)));
typedef float f32x4 __attribute__((ext_vector_type(4)));

__device__ __forceinline__ uint16_t f2bf(float x) {  // RNE float->bf16 (manual)
  uint32_t u = __float_as_uint(x);
  return (uint16_t)((u + 0x7fffu + ((u >> 16) & 1u)) >> 16);
}
__device__ __forceinline__ uint16_t f2bf_fast(float x) {  // RNE via v_cvt (fusable)
  return __builtin_bit_cast(uint16_t, __float2bfloat16(x));
}
__device__ __forceinline__ float bf2f(uint16_t h) {
  return __uint_as_float(((uint32_t)h) << 16);
}
__device__ __forceinline__ float fexp2(float x) {  // v_exp_f32 (2^x)
  return __builtin_amdgcn_exp2f(x);
}

__device__ __forceinline__ void tf_round(uint32_t& x0, uint32_t& x1, const int r) {
  x0 += x1;
  x1 = (x1 << r) | (x1 >> (32 - r));
  x1 ^= x0;
}

// threefry2x32, key(42)=(0,42), counter (0, j), bits = y0^y1  [VERIFIED R2]
__device__ __noinline__ int keep_bit(uint32_t j) {
  uint32_t x0 = 0u, x1 = j;
  const uint32_t k0 = 0u, k1v = 42u;
  const uint32_t k2v = k0 ^ k1v ^ 0x1BD11BDAu;
  x0 += k0; x1 += k1v;
  tf_round(x0, x1, 13); tf_round(x0, x1, 15); tf_round(x0, x1, 26); tf_round(x0, x1, 6);
  x0 += k1v; x1 += k2v + 1u;
  tf_round(x0, x1, 17); tf_round(x0, x1, 29); tf_round(x0, x1, 16); tf_round(x0, x1, 24);
  x0 += k2v; x1 += k0 + 2u;
  tf_round(x0, x1, 13); tf_round(x0, x1, 15); tf_round(x0, x1, 26); tf_round(x0, x1, 6);
  x0 += k0; x1 += k1v + 3u;
  tf_round(x0, x1, 17); tf_round(x0, x1, 29); tf_round(x0, x1, 16); tf_round(x0, x1, 24);
  x0 += k1v; x1 += k2v + 4u;
  tf_round(x0, x1, 13); tf_round(x0, x1, 15); tf_round(x0, x1, 26); tf_round(x0, x1, 6);
  x0 += k2v; x1 += k0 + 5u;
  uint32_t bits = x0 ^ x1;
  float u = __uint_as_float((bits >> 9) | 0x3f800000u) - 1.0f;
  return u < 0.9f;
}

// ---- pre-pass: K split + V transpose, swizzled bf16 tiles (R18: coalesced) ----
__global__ __launch_bounds__(NTF) void prep_kv(const float* __restrict__ K,
                                               const float* __restrict__ V,
                                               uint16_t* __restrict__ Khg,
                                               uint16_t* __restrict__ Klg,
                                               uint16_t* __restrict__ Vtg) {
  __shared__ float Vl[TK][Dn + 1];
  const int t = threadIdx.x;
  const int kt = blockIdx.x;   // 0..15
  const int bh = blockIdx.y;   // 0..63
  const size_t tile = ((size_t)bh * 16 + kt) * 4096;
  const size_t rowbase = (size_t)bh * Sn + (size_t)(kt * TK);

  // Coalesced load: thread t covers row r = i*32+(t>>3), cols (t&7)*8..+7.
  // A wave reads 8 complete 256B rows (2KB contiguous); K-split stores
  // complete each 128B output row via 8 lanes x XOR-permuted 16B chunks.
#pragma unroll
  for (int i = 0; i < 2; ++i) {
    const int r = i * 32 + (t >> 3);
    const int c0 = (t & 7) * 8;
    const float* ksrc = K + (rowbase + (size_t)r) * Dn + c0;
    float4 a = *(const float4*)(ksrc);
    float4 b = *(const float4*)(ksrc + 4);
    float xs[8] = {a.x, a.y, a.z, a.w, b.x, b.y, b.z, b.w};
    s16x8 hv, lv;
#pragma unroll
    for (int j = 0; j < 8; ++j) {
      uint16_t hb = f2bf_fast(xs[j]);
      hv[j] = (short)hb;
      lv[j] = (short)f2bf_fast(xs[j] - bf2f(hb));
    }
    const int sc = (t & 7) ^ (r & 7);   // chunk = c0/8 = t&7 (same formula as R17)
    *(s16x8*)&Khg[tile + (size_t)r * 64 + sc * 8] = hv;
    *(s16x8*)&Klg[tile + (size_t)r * 64 + sc * 8] = lv;
    const float* vsrc = V + (rowbase + (size_t)r) * Dn + c0;
    float4 va = *(const float4*)(vsrc);
    float4 vb = *(const float4*)(vsrc + 4);
    *(float4*)&Vl[r][c0] = va;
    *(float4*)&Vl[r][c0 + 4] = vb;
  }
  __syncthreads();
  // transpose-read phase: verbatim R17 layout (output row = V column d = r)
  {
    const int r = t >> 2, qd = t & 3;
#pragma unroll
    for (int half = 0; half < 2; ++half) {
      s16x8 ov;
#pragma unroll
      for (int j = 0; j < 8; ++j)
        ov[j] = (short)f2bf_fast(Vl[qd * 16 + half * 8 + j][r]);
      const int sc = (qd * 2 + half) ^ (r & 7);
      *(s16x8*)&Vtg[tile + (size_t)r * 64 + sc * 8] = ov;
    }
  }
}

// -------- main flash kernel: S^T orientation, TQ=128, 8 waves, dbuf ping-pong --------
__global__ __launch_bounds__(NT, 4) void attn_mfma7(
    const float* __restrict__ Q, const uint16_t* __restrict__ Khg,
    const uint16_t* __restrict__ Klg, const uint16_t* __restrict__ Vtg,
    const float* __restrict__ V, const int* __restrict__ scale_ptr,
    float* __restrict__ out) {
  __shared__ uint16_t KhS[2][TK * Dn];   // 2 x 8 KB ping-pong (DMA dest, swizzled)
  __shared__ uint16_t KlS[2][TK * Dn];
  __shared__ uint16_t VtS[2][TK * Dn];
  __shared__ uint16_t PS[8 * 16 * 64];   // per-wave P[q][key], XOR-chunk swizzled
  __shared__ uint32_t Lm[8][CAP];        // per-wave candidate list: (rw<<10)|key
  __shared__ float Lsv[8][CAP];          // candidate raw logit s (log2 domain)
  __shared__ float mfin[8][16];          // per-wave final row max (log2 domain)

  const int t = threadIdx.x;
  const int w = t >> 6;                  // 0..7
  const int lane = t & 63;
  const int l16 = lane & 15;
  const int quad = lane >> 4;
  const int xl = l16 & 7;                // XOR swizzle key

  // ---- T1: XCD-aware work permutation. Grid (8,16,4); XCD = linear%8 = x.
  // bh = x*8+(y&7), qb = (y>>3)*4+z  [bijective]: all 8 q-blocks of one bh
  // land on one XCD -> per-XCD ws footprint 3MB fits its 4MB L2. ----
  const int bh = blockIdx.x * 8 + (blockIdx.y & 7);
  const int qb = ((blockIdx.y >> 3) << 2) | blockIdx.z;
  const int qbase = qb * TQM;
  // log2(e) folded into the Q pre-scale: all logits live in the log2 domain.
  const float qscale = (float)(*scale_ptr) * 1.44269504089f;
  const float pthr = 1.670170079e-5f;    // exp(-11), in the p domain (unchanged)

  // per-wave DMA segment: wave w covers elements [w*512, w*512+512) of each tile
  const int eoff = w * 512 + lane * 8;
  const size_t tbase = (size_t)bh * 16 * 4096;
  const int psw = w * 1024;              // per-wave PS base (elements)

  auto issue3 = [&](int ti, int pb) {    // stage Kh,Kl,Vt of tile ti into buf pb
    const size_t tile = tbase + (size_t)ti * 4096;
    __builtin_amdgcn_global_load_lds(
        (const __attribute__((address_space(1))) uint32_t*)(Khg + tile + eoff),
        (__attribute__((address_space(3))) uint32_t*)(&KhS[pb][eoff]), 16, 0, 0);
    __builtin_amdgcn_global_load_lds(
        (const __attribute__((address_space(1))) uint32_t*)(Klg + tile + eoff),
        (__attribute__((address_space(3))) uint32_t*)(&KlS[pb][eoff]), 16, 0, 0);
    __builtin_amdgcn_global_load_lds(
        (const __attribute__((address_space(1))) uint32_t*)(Vtg + tile + eoff),
        (__attribute__((address_space(3))) uint32_t*)(&VtS[pb][eoff]), 16, 0, 0);
  };

  // prologue: tile 0 -> buf0 in flight; Q load/split overlaps it
  issue3(0, 0);

  // ---- Q B-frags (pre-scaled, log2 domain): wave w owns q rows qbase+w*16+l16 ----
  s16x8 qh[2], ql[2];
  {
    const int qrow = qbase + w * 16 + l16;
    const float* src = Q + ((size_t)bh * Sn + (size_t)qrow) * Dn;
#pragma unroll
    for (int ks = 0; ks < 2; ++ks) {
      float4 x0 = *(const float4*)(src + ks * 32 + quad * 8);
      float4 x1 = *(const float4*)(src + ks * 32 + quad * 8 + 4);
      float xv[8] = {x0.x, x0.y, x0.z, x0.w, x1.x, x1.y, x1.z, x1.w};
#pragma unroll
      for (int j = 0; j < 8; ++j) {
        const float xs = xv[j] * qscale;
        uint16_t hb = f2bf_fast(xs);
        qh[ks][j] = (short)hb;
        ql[ks][j] = (short)f2bf_fast(xs - bf2f(hb));
      }
    }
  }

  // per-lane softmax state: ONE q per lane (log2 domain)
  float m_r = -INFINITY, l_r = 0.0f;
  // O^T accumulator: o_acc[c][r] = O[q = l16][dv = c*16+quad*4+r]
  f32x4 o_acc[4];
#pragma unroll
  for (int c = 0; c < 4; ++c) o_acc[c] = (f32x4){0.f, 0.f, 0.f, 0.f};

  const uint32_t hbase = (uint32_t)bh * (uint32_t)Sn;
  int lbase = 0;  // per-wave list fill (wave-uniform)

  // one tile's QK -> softmax -> PV, reading buffers [pb]
  auto tile_step = [&](int kbase, int pb) {
    // ---- S^T = K Q^T: A = K tile (LDS), B = Q (regs), split-bf16 3-MFMA ----
    f32x4 sacc[4];
#pragma unroll
    for (int c = 0; c < 4; ++c) sacc[c] = (f32x4){0.f, 0.f, 0.f, 0.f};
    __builtin_amdgcn_s_setprio(1);     // T5: favor MFMA cluster
#pragma unroll
    for (int ks = 0; ks < 2; ++ks) {
#pragma unroll
      for (int c = 0; c < 4; ++c) {
        const int boff = (c * 16 + l16) * 64 + (((ks * 4 + quad) ^ xl) * 8);
        const s16x8 khv = *(const s16x8*)&KhS[pb][boff];
        const s16x8 klv = *(const s16x8*)&KlS[pb][boff];
        sacc[c] = __builtin_amdgcn_mfma_f32_16x16x32_bf16(khv, qh[ks], sacc[c], 0, 0, 0);
        sacc[c] = __builtin_amdgcn_mfma_f32_16x16x32_bf16(khv, ql[ks], sacc[c], 0, 0, 0);
        sacc[c] = __builtin_amdgcn_mfma_f32_16x16x32_bf16(klv, qh[ks], sacc[c], 0, 0, 0);
      }
    }
    __builtin_amdgcn_s_setprio(0);

    // ---- online softmax (per-lane row state), fused push + P store ----
    {
      float mx = sacc[0][0];
#pragma unroll
      for (int c = 0; c < 4; ++c)
#pragma unroll
        for (int r = 0; r < 4; ++r) mx = fmaxf(mx, sacc[c][r]);
      mx = fmaxf(mx, __shfl_xor(mx, 16));
      mx = fmaxf(mx, __shfl_xor(mx, 32));  // row max over all 64 keys of tile

      // defer-rescale: if no lane's max grew, alpha==1 exactly -> skip the pass
      if (__ballot(mx > m_r) != 0ull) {
        const float mn = fmaxf(m_r, mx);
        const float al = fexp2(m_r - mn);  // 0 on first tile
        m_r = mn;
#pragma unroll
        for (int c = 0; c < 4; ++c)
#pragma unroll
          for (int r = 0; r < 4; ++r) o_acc[c][r] *= al;
        l_r *= al;
      }

      // -15.88 < -11*log2(e): gate true whenever any pc can exceed pthr
      const bool anyhot = __ballot(mx - m_r > -15.88f) != 0ull;
      float rs = 0.0f;
#pragma unroll
      for (int c = 0; c < 4; ++c) {
        float pc[4];  // only 4 floats live at the pressure peak (reg diet)
#pragma unroll
        for (int r = 0; r < 4; ++r) {
          pc[r] = fexp2(sacc[c][r] - m_r);
          rs += pc[r];  // UNMASKED row sum (softmax normalizes before dropout)
        }
        if (anyhot) {
#pragma unroll
          for (int r = 0; r < 4; ++r) {
            const uint64_t mc = __ballot(pc[r] > pthr);
            if (mc != 0ull) {
              if (lbase + 64 <= CAP) {
                const int slot = lbase + (int)__popcll(mc & ((1ull << lane) - 1ull));
                if (pc[r] > pthr) {
                  Lm[w][slot] = ((uint32_t)l16 << 10) |
                                (uint32_t)(kbase + c * 16 + quad * 4 + r);
                  Lsv[w][slot] = sacc[c][r];  // raw logit (log2 domain)
                }
                lbase += (int)__popcll(mc);
              } else if (pc[r] > pthr) {  // overflow: inline exact dropout
                const uint32_t j =
                    (hbase + (uint32_t)(qbase + w * 16 + l16)) * (uint32_t)Sn +
                    (uint32_t)(kbase + c * 16 + quad * 4 + r);
                if (!keep_bit(j)) pc[r] = 0.0f;  // rs already added (unmasked)
              }
            }
          }
        }
        // P store: 4 consecutive keys -> b64, XOR-chunk swizzled (native cvt)
        s16x4 pk;
#pragma unroll
        for (int r = 0; r < 4; ++r) pk[r] = (short)f2bf_fast(pc[r]);
        const int pos = (c * 2 + (quad >> 1)) ^ xl;
        *(s16x4*)&PS[psw + l16 * 64 + pos * 8 + (quad & 1) * 4] = pk;
      }

      rs += __shfl_xor(rs, 16);
      rs += __shfl_xor(rs, 32);
      l_r += rs;
    }

    // ---- PV as O^T: A = Vt (LDS), B = P (LDS, same-wave RAW) ----
    __builtin_amdgcn_s_setprio(1);     // T5
#pragma unroll
    for (int ks2 = 0; ks2 < 2; ++ks2) {
      const s16x8 pfr = *(const s16x8*)&PS[psw + l16 * 64 + (((ks2 * 4 + quad) ^ xl) * 8)];
#pragma unroll
      for (int c = 0; c < 4; ++c) {
        const int voff = (c * 16 + l16) * 64 + (((ks2 * 4 + quad) ^ xl) * 8);
        const s16x8 vb = *(const s16x8*)&VtS[pb][voff];
        o_acc[c] = __builtin_amdgcn_mfma_f32_16x16x32_bf16(vb, pfr, o_acc[c], 0, 0, 0);
      }
    }
    __builtin_amdgcn_s_setprio(0);
  };

  // ---- ping-pong main loop: ONE barrier per tile, prefetch into other buffer ----
  for (int kt = 0; kt < NTILE; kt += 2) {
    __syncthreads();               // own vmcnt(0) drained -> buf0(kt) visible to all;
                                   // all waves done reading buf1 (tile kt-1)
    issue3(kt + 1, 1);             // kt+1 <= 15 always (NTILE even)
    tile_step(kt * TK, 0);
    __syncthreads();               // buf1(kt+1) visible; all done reading buf0(kt)
    if (kt + 2 < NTILE) issue3(kt + 2, 0);
    tile_step((kt + 1) * TK, 1);
  }

  // ---- drain: dense threefry over candidate list, subtract dropped p*V ----
  if (quad == 0) mfin[w][l16] = m_r;
  for (int e0 = 0; e0 < lbase; e0 += 64) {
    const int e = e0 + lane;
    const bool valid = e < lbase;
    const uint32_t meta = valid ? Lm[w][e] : 0u;
    const float sv = valid ? Lsv[w][e] : 0.0f;
    const uint32_t rwv = meta >> 10, keyv = meta & 1023u;
    const uint32_t grow = (uint32_t)(qbase + w * 16) + rwv;
    const uint32_t j = (hbase + grow) * (uint32_t)Sn + keyv;
    const int kb = keep_bit(j);  // dense: all 64 lanes productive
    uint64_t dm = __ballot(valid && !kb);
    while (dm != 0ull) {
      const int src = (int)__builtin_ctzll(dm);
      dm &= dm - 1ull;
      const uint32_t meta_s = (uint32_t)__builtin_amdgcn_readlane((int)meta, src);
      const float sv_s =
          __uint_as_float((uint32_t)__builtin_amdgcn_readlane((int)__float_as_uint(sv), src));
      const int rw = (int)(meta_s >> 10);
      const int key = (int)(meta_s & 1023u);
      const float p = fexp2(sv_s - mfin[w][rw]);   // log2 domain
      const float pb2 = bf2f(f2bf_fast(p));        // matches stored bf16(P) bits
      if (rw == l16) {  // the 4 quads owning column q participate
        const float* vp = V + ((size_t)bh * Sn + (size_t)key) * Dn;
#pragma unroll
        for (int c = 0; c < 4; ++c) {
          float4 vv = *(const float4*)(vp + c * 16 + quad * 4);
          o_acc[c][0] = fmaf(-pb2, bf2f(f2bf(vv.x)), o_acc[c][0]);
          o_acc[c][1] = fmaf(-pb2, bf2f(f2bf(vv.y)), o_acc[c][1]);
          o_acc[c][2] = fmaf(-pb2, bf2f(f2bf(vv.z)), o_acc[c][2]);
          o_acc[c][3] = fmaf(-pb2, bf2f(f2bf(vv.w)), o_acc[c][3]);
        }
      }
    }
  }

  // ---- epilogue: out[q][dv] = O^T / (l * 0.9); per-lane scalar scale ----
  {
    const float inv = 1.0f / (l_r * 0.9f);
    const size_t obase = ((size_t)bh * Sn + (size_t)(qbase + w * 16 + l16)) * Dn;
#pragma unroll
    for (int c = 0; c < 4; ++c) {
      float4 ov;
      ov.x = o_acc[c][0] * inv;
      ov.y = o_acc[c][1] * inv;
      ov.z = o_acc[c][2] * inv;
      ov.w = o_acc[c][3] * inv;
      *(float4*)(out + obase + c * 16 + quad * 4) = ov;
    }
  }
}

// ---------------- fallback (R3 kernel, verbatim): used only if ws too small ----------------
constexpr int KST = 72;
__global__ __launch_bounds__(NTF) void attn_fallback(
    const float* __restrict__ Q, const float* __restrict__ K,
    const float* __restrict__ V, const int* __restrict__ scale_ptr,
    float* __restrict__ out) {
  __shared__ uint16_t KhS[64 * KST];
  __shared__ uint16_t KlS[64 * KST];
  __shared__ uint16_t VtS[Dn * KST];
  __shared__ uint16_t PSf[4 * 16 * KST];

  const int t = threadIdx.x;
  const int w = t >> 6;
  const int lane = t & 63;
  const int l16 = lane & 15;
  const int quad = lane >> 4;
  const int b = blockIdx.z, h = blockIdx.y;
  const int qbase = blockIdx.x * 64;
  const size_t bh = (size_t)b * Hn + h;
  const float scale = (float)(*scale_ptr);
  const float* Kp = K + bh * Sn * Dn;
  const float* Vp = V + bh * Sn * Dn;

  const int qrow = qbase + w * 16 + l16;
  const float* Qp = Q + (bh * Sn + (size_t)qrow) * Dn;
  s16x8 qh[2], ql[2];
#pragma unroll
  for (int ks = 0; ks < 2; ++ks) {
    const float* src = Qp + ks * 32 + quad * 8;
    float4 x0 = *(const float4*)(src);
    float4 x1 = *(const float4*)(src + 4);
    float xv[8] = {x0.x, x0.y, x0.z, x0.w, x1.x, x1.y, x1.z, x1.w};
#pragma unroll
    for (int j = 0; j < 8; ++j) {
      uint16_t hb = f2bf(xv[j]);
      qh[ks][j] = (short)hb;
      ql[ks][j] = (short)f2bf(xv[j] - bf2f(hb));
    }
  }
  const int kr = t >> 2;
  const int qd = t & 3;
  float m_r[4], l_r[4];
#pragma unroll
  for (int r = 0; r < 4; ++r) { m_r[r] = -INFINITY; l_r[r] = 0.0f; }
  f32x4 o_acc[4];
#pragma unroll
  for (int c = 0; c < 4; ++c) o_acc[c] = (f32x4){0.f, 0.f, 0.f, 0.f};
  const uint32_t rowlin = ((uint32_t)(b * Hn + h)) * (uint32_t)Sn +
                          (uint32_t)(qbase + w * 16 + quad * 4);
  for (int kt = 0; kt < Sn / 64; ++kt) {
    const int kbase = kt * 64;
    __syncthreads();
    {
      const float* ksrc = Kp + (size_t)(kbase + kr) * Dn + qd * 16;
#pragma unroll
      for (int half = 0; half < 2; ++half) {
        float4 a = *(const float4*)(ksrc + half * 8);
        float4 b2 = *(const float4*)(ksrc + half * 8 + 4);
        float xs[8] = {a.x, a.y, a.z, a.w, b2.x, b2.y, b2.z, b2.w};
        s16x8 hv, lv;
#pragma unroll
        for (int j = 0; j < 8; ++j) {
          uint16_t hb = f2bf(xs[j]);
          hv[j] = (short)hb;
          lv[j] = (short)f2bf(xs[j] - bf2f(hb));
        }
        *(s16x8*)&KhS[kr * KST + qd * 16 + half * 8] = hv;
        *(s16x8*)&KlS[kr * KST + qd * 16 + half * 8] = lv;
      }
      const float* vsrc = Vp + (size_t)(kbase + kr) * Dn + qd * 16;
#pragma unroll
      for (int half = 0; half < 2; ++half) {
        float4 a = *(const float4*)(vsrc + half * 8);
        float4 b2 = *(const float4*)(vsrc + half * 8 + 4);
        float xs[8] = {a.x, a.y, a.z, a.w, b2.x, b2.y, b2.z, b2.w};
#pragma unroll
        for (int j = 0; j < 8; ++j)
          VtS[(qd * 16 + half * 8 + j) * KST + kr] = f2bf(xs[j]);
      }
    }
    __syncthreads();
    f32x4 sacc[4];
#pragma unroll
    for (int c = 0; c < 4; ++c) sacc[c] = (f32x4){0.f, 0.f, 0.f, 0.f};
#pragma unroll
    for (int ks = 0; ks < 2; ++ks) {
#pragma unroll
      for (int c = 0; c < 4; ++c) {
        const s16x8 bh_ = *(const s16x8*)&KhS[(c * 16 + l16) * KST + ks * 32 + quad * 8];
        const s16x8 bl_ = *(const s16x8*)&KlS[(c * 16 + l16) * KST + ks * 32 + quad * 8];
        sacc[c] = __builtin_amdgcn_mfma_f32_16x16x32_bf16(qh[ks], bh_, sacc[c], 0, 0, 0);
        sacc[c] = __builtin_amdgcn_mfma_f32_16x16x32_bf16(ql[ks], bh_, sacc[c], 0, 0, 0);
        sacc[c] = __builtin_amdgcn_mfma_f32_16x16x32_bf16(qh[ks], bl_, sacc[c], 0, 0, 0);
      }
    }
    float mx[4];
#pragma unroll
    for (int r = 0; r < 4; ++r) {
      mx[r] = sacc[0][r] * scale;
#pragma unroll
      for (int c = 1; c < 4; ++c) mx[r] = fmaxf(mx[r], sacc[c][r] * scale);
#pragma unroll
      for (int d = 1; d < 16; d <<= 1) mx[r] = fmaxf(mx[r], __shfl_xor(mx[r], d));
    }
    float al[4];
#pragma unroll
    for (int r = 0; r < 4; ++r) {
      const float mn = fmaxf(m_r[r], mx[r]);
      al[r] = __expf(m_r[r] - mn);
      m_r[r] = mn;
    }
#pragma unroll
    for (int c = 0; c < 4; ++c)
#pragma unroll
      for (int r = 0; r < 4; ++r) o_acc[c][r] *= al[r];
    float rs[4] = {0.f, 0.f, 0.f, 0.f};
#pragma unroll
    for (int c = 0; c < 4; ++c) {
#pragma unroll
      for (int r = 0; r < 4; ++r) {
        const float d = sacc[c][r] * scale - m_r[r];
        float pv = __expf(d);
        rs[r] += pv;
        if (d > -25.0f) {
          const uint32_t j = (rowlin + (uint32_t)r) * (uint32_t)Sn +
                             (uint32_t)(kbase + c * 16 + l16);
          if (!keep_bit(j)) pv = 0.0f;
        }
        PSf[(w * 16 + quad * 4 + r) * KST + c * 16 + l16] = f2bf(pv);
      }
    }
#pragma unroll
    for (int r = 0; r < 4; ++r) {
#pragma unroll
      for (int d = 1; d < 16; d <<= 1) rs[r] += __shfl_xor(rs[r], d);
      l_r[r] = l_r[r] * al[r] + rs[r];
    }
#pragma unroll
    for (int ks2 = 0; ks2 < 2; ++ks2) {
      const s16x8 pa = *(const s16x8*)&PSf[(w * 16 + l16) * KST + ks2 * 32 + quad * 8];
#pragma unroll
      for (int c = 0; c < 4; ++c) {
        const s16x8 vb = *(const s16x8*)&VtS[(c * 16 + l16) * KST + ks2 * 32 + quad * 8];
        o_acc[c] = __builtin_amdgcn_mfma_f32_16x16x32_bf16(pa, vb, o_acc[c], 0, 0, 0);
      }
    }
  }
  float inv[4];
#pragma unroll
  for (int r = 0; r < 4; ++r) inv[r] = 1.0f / (l_r[r] * 0.9f);
#pragma unroll
  for (int c = 0; c < 4; ++c)
#pragma unroll
    for (int r = 0; r < 4; ++r)
      out[(bh * Sn + (size_t)(qbase + w * 16 + quad * 4 + r)) * Dn + c * 16 + l16] =
          o_acc[c][r] * inv[r];
}

extern "C" void kernel_launch(void* const* d_in, const int* in_sizes, int n_in,
                              void* d_out, int out_size, void* d_ws, size_t ws_size,
                              hipStream_t stream) {
  const float* Q = (const float*)d_in[0];
  const float* K = (const float*)d_in[1];
  const float* V = (const float*)d_in[2];
  const int* sf = (const int*)d_in[3];
  float* out = (float*)d_out;

  constexpr size_t ARR = (size_t)Bn * Hn * Sn * Dn;  // 4,194,304 elems (8 MB bf16)
  const size_t need = 3 * ARR * sizeof(uint16_t);    // 24 MB

  if (ws_size >= need) {
    uint16_t* Khg = (uint16_t*)d_ws;
    uint16_t* Klg = Khg + ARR;
    uint16_t* Vtg = Klg + ARR;
    prep_kv<<<dim3(16, 64), NTF, 0, stream>>>(K, V, Khg, Klg, Vtg);
    attn_mfma7<<<dim3(Sn / TQM, Hn, Bn), NT, 0, stream>>>(Q, Khg, Klg, Vtg, V, sf, out);
  } else {
    attn_fallback<<<dim3(Sn / 64, Hn, Bn), NTF, 0, stream>>>(Q, K, V, sf, out);
  }
}